// Round 14
// baseline (227.760 us; speedup 1.0000x reference)
//
#include <hip/hip_runtime.h>
#include <math.h>

#define BN_INV_F 0.9999950000374997f

__device__ __forceinline__ void gload_lds4(const float* g, float* l) {
    __builtin_amdgcn_global_load_lds(
        (const __attribute__((address_space(1))) void*)g,
        (__attribute__((address_space(3))) void*)l, 4, 0, 0);
}
__device__ __forceinline__ void gload_lds16(const float* g, float* l) {
    __builtin_amdgcn_global_load_lds(
        (const __attribute__((address_space(1))) void*)g,
        (__attribute__((address_space(3))) void*)l, 16, 0, 0);
}

// ---------------------------------------------------------------------------
// Weight transpose (once): wt[(cin*9+k)*COUT + co] = w[co][cin][k]
// ---------------------------------------------------------------------------
__global__ __launch_bounds__(256) void wtrans_all_k(
    const float* __restrict__ w1, const float* __restrict__ w2,
    const float* __restrict__ w3, const float* __restrict__ wp,
    float* __restrict__ w1t, float* __restrict__ w2t,
    float* __restrict__ w3t, float* __restrict__ wpt)
{
    int i = blockIdx.x * 256 + threadIdx.x;
    if (i < 144) {
        int co = i % 16, k = i / 16;
        w1t[i] = w1[co * 9 + k];
    } else if (i < 4752) {
        int t = i - 144;
        int co = t % 32, rk = t / 32, cin = rk / 9, k = rk % 9;
        w2t[t] = w2[(co * 16 + cin) * 9 + k];
    } else if (i < 23184) {
        int t = i - 4752;
        int co = t % 64, rk = t / 64, cin = rk / 9, k = rk % 9;
        w3t[t] = w3[(co * 32 + cin) * 9 + k];
    } else if (i < 60048) {
        int t = i - 23184;
        int co = t % 64, rk = t / 64, cin = rk / 9, k = rk % 9;
        wpt[t] = wp[(co * 64 + cin) * 9 + k];
    }
}

// ---------------------------------------------------------------------------
// Original conv body (conv1 / pc): thread-split couts (COB per thread).
// ---------------------------------------------------------------------------
template <int CIN, int CINB, int COUT, int COB, int HIN, int HOUT, int STRIDE,
          int TW, int ROWS_T, int PPT, int CB, int NTHREADS,
          bool BN_RELU, bool SE_SUM, int HSE_IN, int KSPLIT>
__device__ __forceinline__ void conv_body(
    const float* __restrict__ in, const float* __restrict__ wt,
    const float* __restrict__ gamma, const float* __restrict__ beta,
    float* __restrict__ out, size_t pstride,
    float* __restrict__ se_sum, const float* __restrict__ se_sums_in,
    const float* __restrict__ se_w1, const float* __restrict__ se_b1,
    const float* __restrict__ se_w2, const float* __restrict__ se_b2,
    float inv_spatial)
{
    constexpr int WIN = HIN, WOUT = HOUT;
    constexpr int TH = ROWS_T * PPT;
    constexpr int IH_T = (TH - 1) * STRIDE + 3;
    constexpr int NW = NTHREADS / 64;
    constexpr int NCHUNK = CINB / CB;
    constexpr int SEGS = (WIN >= 64) ? (WIN / 64) : 1;
    constexpr int PAIRS = (IH_T + 1) / 2;
    constexpr int NG = COUT / COB;
    constexpr int IHW = IH_T * WIN;
    constexpr int CHUNK_BYTES = CB * IHW * 4;
    constexpr bool FAST16 = (CHUNK_BYTES % 1024) == 0;
    constexpr int NISS = CHUNK_BYTES / 1024;
    static_assert(NTHREADS == TW * ROWS_T, "geometry");
    static_assert(TW == WOUT, "tile must span full output width");
    static_assert(CINB % CB == 0, "chunking");
    static_assert(WIN % 64 == 0 || WIN == 32, "stage width");

    const int b = blockIdx.z;
    const int gy = blockIdx.y;
    const int ty = blockIdx.x;
    const int tid = threadIdx.x;
    const int wo = tid % TW;
    const int rg = tid / TW;
    const int g = gy % NG;
    const int kk = gy / NG;
    const int cin0 = kk * CINB;

    __shared__ float in_t[2][CB * IH_T * WIN];
    __shared__ float scl[CIN];
    __shared__ float gl[COB], bl[COB];
    __shared__ float red[NW][COB];
    __shared__ float hid[HSE_IN > 0 ? HSE_IN : 1];

    const float* inb = in + (size_t)b * CIN * HIN * WIN;
    const int gr0 = ty * TH * STRIDE - 1;
    const int wos = wo * STRIDE;
    const int wvid = tid >> 6, lane = tid & 63;
    const bool interior = (gr0 >= 0) && (gr0 + IH_T <= HIN);

    auto stage = [&](int c, int buf) {
        const int cb0 = cin0 + c * CB;
        float* bb = &in_t[buf][0];
        if (FAST16 && interior) {
            for (int i = wvid; i < NISS; i += NW) {
                int fe = i * 256 + lane * 4;
                int ci = fe / IHW;
                int rem = fe - ci * IHW;
                int lr = rem / WIN;
                int lc = rem - lr * WIN;
                const float* gsrc = inb + (size_t)(cb0 + ci) * (HIN * WIN)
                                  + (size_t)(gr0 + lr) * WIN + lc;
                gload_lds16(gsrc, bb + i * 256);
            }
        } else if (WIN >= 64) {
            for (int r = wvid; r < CB * IH_T; r += NW) {
                int ci = r / IH_T, lr = r - ci * IH_T;
                int gr = gr0 + lr;
                float* ldst = bb + (ci * IH_T + lr) * WIN;
                if (gr >= 0 && gr < HIN) {
                    const float* gsrc = inb + (size_t)(cb0 + ci) * HIN * WIN + (size_t)gr * WIN;
#pragma unroll
                    for (int s = 0; s < SEGS; ++s)
                        gload_lds4(gsrc + s * 64 + lane, ldst + s * 64);
                } else {
#pragma unroll
                    for (int s = 0; s < SEGS; ++s) ldst[s * 64 + lane] = 0.0f;
                }
            }
        } else {
            for (int pz = wvid; pz < CB * PAIRS; pz += NW) {
                int ci = pz / PAIRS, q = pz - ci * PAIRS;
                int lr0 = q * 2;
                int nr = (lr0 + 1 < IH_T) ? 2 : 1;
                int grr = gr0 + lr0;
                float* ldst = bb + (ci * IH_T + lr0) * WIN;
                if (nr == 2 && grr >= 0 && grr + 1 < HIN) {
                    const float* gsrc = inb + (size_t)(cb0 + ci) * HIN * WIN + (size_t)grr * WIN + lane;
                    gload_lds4(gsrc, ldst);
                } else {
                    for (int e = lane; e < nr * WIN; e += 64) {
                        int rr = e / WIN, cc = e - rr * WIN;
                        int gr = grr + rr;
                        ldst[e] = (gr >= 0 && gr < HIN)
                            ? inb[(size_t)(cb0 + ci) * HIN * WIN + (size_t)gr * WIN + cc] : 0.0f;
                    }
                }
            }
        }
    };

    stage(0, 0);

    if (HSE_IN > 0) {
        if (tid < HSE_IN) {
            float a = se_b1[tid];
            for (int c = 0; c < CIN; ++c)
                a = fmaf(se_sums_in[b * CIN + c] * inv_spatial, se_w1[tid * CIN + c], a);
            hid[tid] = fmaxf(a, 0.0f);
        }
        __syncthreads();
        if (tid < CIN) {
            float a = se_b2[tid];
            for (int h = 0; h < HSE_IN; ++h)
                a = fmaf(hid[h], se_w2[tid * HSE_IN + h], a);
            scl[tid] = 1.0f / (1.0f + expf(-a));
        }
    } else {
        for (int t = tid; t < CIN; t += NTHREADS) scl[t] = 1.0f;
    }
    if (tid < COB) {
        int co = g * COB + tid;
        if (BN_RELU) {
            gl[tid] = gamma[co] * BN_INV_F;
            bl[tid] = beta[co];
        } else {
            gl[tid] = (kk == 0) ? gamma[co] : 0.0f;
        }
    }

    float acc[PPT][COB];
#pragma unroll
    for (int p = 0; p < PPT; ++p)
#pragma unroll
        for (int co = 0; co < COB; ++co) acc[p][co] = 0.0f;

    int cur = 0;
    for (int c = 0; c < NCHUNK; ++c) {
        asm volatile("s_waitcnt vmcnt(0)" ::: "memory");
        __syncthreads();
        if (c + 1 < NCHUNK) stage(c + 1, cur ^ 1);

        const float* bb = &in_t[cur][0];
#pragma unroll
        for (int ci = 0; ci < CB; ++ci) {
            const int cw = cin0 + c * CB + ci;
            const float sc = scl[cw];
            const float* wtap = wt + (size_t)cw * 9 * COUT + g * COB;
            const float* bb_ci = bb + ci * IH_T * WIN;
#pragma unroll
            for (int kh = 0; kh < 3; ++kh) {
#pragma unroll
                for (int kw = 0; kw < 3; ++kw) {
                    const float* wrow = wtap + (kh * 3 + kw) * COUT;
#pragma unroll
                    for (int p = 0; p < PPT; ++p) {
                        const float* row = bb_ci + ((rg + p * ROWS_T) * STRIDE + kh) * WIN;
                        int wi = wos + kw - 1;
                        float v;
                        if (kw == 0) {
                            v = row[wi < 0 ? 0 : wi];
                            if (wi < 0) v = 0.0f;
                        } else if (STRIDE == 1 && kw == 2) {
                            v = row[wi >= WIN ? WIN - 1 : wi];
                            if (wi >= WIN) v = 0.0f;
                        } else {
                            v = row[wi];
                        }
                        v *= sc;
#pragma unroll
                        for (int co = 0; co < COB; ++co)
                            acc[p][co] = fmaf(wrow[co], v, acc[p][co]);
                    }
                }
            }
        }
        cur ^= 1;
    }

    float tsum[COB];
#pragma unroll
    for (int co = 0; co < COB; ++co) tsum[co] = 0.0f;
    float* ob = out + (size_t)kk * pstride
              + ((size_t)b * COUT + (size_t)g * COB) * HOUT * WOUT;
#pragma unroll
    for (int p = 0; p < PPT; ++p) {
        const int ho = ty * TH + rg + p * ROWS_T;
#pragma unroll
        for (int co = 0; co < COB; ++co) {
            float v;
            if (BN_RELU)
                v = fmaxf(fmaf(acc[p][co], gl[co], bl[co]), 0.0f);
            else
                v = acc[p][co] + gl[co];
            ob[(size_t)co * HOUT * WOUT + ho * WOUT + wo] = v;
            tsum[co] += v;
        }
    }

    if (SE_SUM) {
#pragma unroll
        for (int co = 0; co < COB; ++co) {
            float v = tsum[co];
            for (int off = 32; off; off >>= 1) v += __shfl_down(v, off, 64);
            if (lane == 0) red[wvid][co] = v;
        }
        __syncthreads();
        if (tid < COB) {
            float v = 0.0f;
#pragma unroll
            for (int k = 0; k < NW; ++k) v += red[k][tid];
            atomicAdd(&se_sum[b * COUT + g * COB + tid], v);
        }
    }
}

// ---------------------------------------------------------------------------
// Wave-split conv body (conv2 / conv3), STRIDE==2 only. Each WAVE owns WCO
// couts over the whole tile. Input staged DE-INTERLEAVED per row:
// [even cols | odd cols] so stride-2 reads are unit-stride (bank-conflict-free).
// ---------------------------------------------------------------------------
template <int CIN, int CINB, int COUT, int WCO, int HIN, int HOUT, int STRIDE,
          int TW, int PPT, int CB, int NTHREADS,
          bool BN_RELU, bool SE_SUM, int HSE_IN, int KSPLIT>
__device__ __forceinline__ void conv_ws_body(
    const float* __restrict__ in, const float* __restrict__ wt,
    const float* __restrict__ gamma, const float* __restrict__ beta,
    float* __restrict__ out, size_t pstride,
    float* __restrict__ se_sum, const float* __restrict__ se_sums_in,
    const float* __restrict__ se_w1, const float* __restrict__ se_b1,
    const float* __restrict__ se_w2, const float* __restrict__ se_b2,
    float inv_spatial)
{
    constexpr int WIN = HIN, WOUT = HOUT;
    constexpr int NW = NTHREADS / 64;
    constexpr int WROWS = 64 / TW;
    constexpr int TH = WROWS * PPT;
    constexpr int IH_T = (TH - 1) * STRIDE + 3;
    constexpr int COBT = NW * WCO;
    constexpr int NG = COUT / COBT;
    constexpr int NCHUNK = CINB / CB;
    constexpr int SEGS = WIN / 64;
    constexpr int HALF = WIN / 2;
    constexpr int IHW = IH_T * WIN;
    static_assert(STRIDE == 2, "wave-split body is stride-2 only");
    static_assert(TW == WOUT, "tile spans full width");
    static_assert(CINB % CB == 0, "chunking");
    static_assert(WIN % 64 == 0, "stage width");
    static_assert(COUT % COBT == 0, "cout split");

    const int b = blockIdx.z;
    const int gy = blockIdx.y;
    const int ty = blockIdx.x;
    const int tid = threadIdx.x;
    const int lane = tid & 63;
    const int wvu = __builtin_amdgcn_readfirstlane(tid >> 6);
    const int wo = lane % TW;
    const int rl = lane / TW;
    const int g = gy % NG;
    const int kk = gy / NG;
    const int cin0 = kk * CINB;

    __shared__ float in_t[2][CB * IH_T * WIN];
    __shared__ float scl[CIN];
    __shared__ float gl[COBT], bl[COBT];
    __shared__ float red[NW][WCO];
    __shared__ float hid[HSE_IN > 0 ? HSE_IN : 1];

    const float* inb = in + (size_t)b * CIN * HIN * WIN;
    const int gr0 = ty * TH * STRIDE - 1;
    const bool interiorNA = false; (void)interiorNA;

    // de-interleaved staging: LDS row = [E(HALF) | O(HALF)]; 4B DMA, per-lane src
    auto stage = [&](int c, int buf) {
        const int cb0 = cin0 + c * CB;
        float* bb = &in_t[buf][0];
        for (int r = wvu; r < CB * IH_T; r += NW) {
            int ci = r / IH_T, lr = r - ci * IH_T;
            int gr = gr0 + lr;
            float* ldst = bb + (ci * IH_T + lr) * WIN;
            if (gr >= 0 && gr < HIN) {
                const float* gsrc = inb + (size_t)(cb0 + ci) * HIN * WIN + (size_t)gr * WIN;
#pragma unroll
                for (int s = 0; s < SEGS; ++s) {
                    int p = s * 64 + lane;
                    int half = p / HALF;
                    int idx = p - half * HALF;
                    gload_lds4(gsrc + 2 * idx + half, ldst + s * 64);
                }
            } else {
#pragma unroll
                for (int s = 0; s < SEGS; ++s) ldst[s * 64 + lane] = 0.0f;
            }
        }
    };

    stage(0, 0);

    if (HSE_IN > 0) {
        if (tid < HSE_IN) {
            float a = se_b1[tid];
            for (int c = 0; c < CIN; ++c)
                a = fmaf(se_sums_in[b * CIN + c] * inv_spatial, se_w1[tid * CIN + c], a);
            hid[tid] = fmaxf(a, 0.0f);
        }
        __syncthreads();
        if (tid < CIN) {
            float a = se_b2[tid];
            for (int h = 0; h < HSE_IN; ++h)
                a = fmaf(hid[h], se_w2[tid * HSE_IN + h], a);
            scl[tid] = 1.0f / (1.0f + expf(-a));
        }
    } else {
        for (int t = tid; t < CIN; t += NTHREADS) scl[t] = 1.0f;
    }
    if (tid < COBT) {
        int co = g * COBT + tid;
        if (BN_RELU) {
            gl[tid] = gamma[co] * BN_INV_F;
            bl[tid] = beta[co];
        } else {
            gl[tid] = (kk == 0) ? gamma[co] : 0.0f;
        }
    }

    float acc[PPT][WCO];
#pragma unroll
    for (int p = 0; p < PPT; ++p)
#pragma unroll
        for (int co = 0; co < WCO; ++co) acc[p][co] = 0.0f;

    int cur = 0;
    for (int c = 0; c < NCHUNK; ++c) {
        asm volatile("s_waitcnt vmcnt(0)" ::: "memory");
        __syncthreads();
        if (c + 1 < NCHUNK) stage(c + 1, cur ^ 1);

        const float* bb = &in_t[cur][0];
#pragma unroll
        for (int ci = 0; ci < CB; ++ci) {
            const int cw = cin0 + c * CB + ci;
            const float sc = scl[cw];
            const float* wtap = wt + (size_t)cw * 9 * COUT + g * COBT + wvu * WCO;
            const float* bb_ci = bb + ci * IH_T * WIN;
#pragma unroll
            for (int kh = 0; kh < 3; ++kh) {
                // per-p reads: E[wo], O[wo-1], O[wo] — unit-stride, conflict-free
                float iwv[PPT][3];
#pragma unroll
                for (int p = 0; p < PPT; ++p) {
                    const float* row = bb_ci + ((rl + p * WROWS) * STRIDE + kh) * WIN;
                    float e  = row[wo];
                    float om = row[HALF + ((wo == 0) ? 0 : wo - 1)];
                    if (wo == 0) om = 0.0f;
                    float op = row[HALF + wo];
                    iwv[p][0] = om * sc;
                    iwv[p][1] = e * sc;
                    iwv[p][2] = op * sc;
                }
#pragma unroll
                for (int kw = 0; kw < 3; ++kw) {
                    const float* wrow = wtap + (kh * 3 + kw) * COUT;  // uniform -> SGPR
#pragma unroll
                    for (int p = 0; p < PPT; ++p) {
                        const float v = iwv[p][kw];
#pragma unroll
                        for (int co = 0; co < WCO; ++co)
                            acc[p][co] = fmaf(wrow[co], v, acc[p][co]);
                    }
                }
            }
        }
        cur ^= 1;
    }

    float tsum[WCO];
#pragma unroll
    for (int co = 0; co < WCO; ++co) tsum[co] = 0.0f;
    float* ob = out + (size_t)kk * pstride
              + ((size_t)b * COUT + (size_t)g * COBT + (size_t)wvu * WCO) * HOUT * WOUT;
#pragma unroll
    for (int p = 0; p < PPT; ++p) {
        const int ho = ty * TH + rl + p * WROWS;
#pragma unroll
        for (int co = 0; co < WCO; ++co) {
            float v;
            if (BN_RELU)
                v = fmaxf(fmaf(acc[p][co], gl[wvu * WCO + co], bl[wvu * WCO + co]), 0.0f);
            else
                v = acc[p][co] + gl[wvu * WCO + co];
            ob[(size_t)co * HOUT * WOUT + ho * WOUT + wo] = v;
            tsum[co] += v;
        }
    }

    if (SE_SUM) {
#pragma unroll
        for (int co = 0; co < WCO; ++co) {
            float v = tsum[co];
            for (int off = 32; off; off >>= 1) v += __shfl_down(v, off, 64);
            if (lane == 0) red[wvu][co] = v;
        }
        __syncthreads();
        if (lane < WCO)
            atomicAdd(&se_sum[b * COUT + g * COBT + wvu * WCO + lane], red[wvu][lane]);
    }
}

#define CONV_ARGS \
    const float* __restrict__ in, const float* __restrict__ wt, \
    const float* __restrict__ gamma, const float* __restrict__ beta, \
    float* __restrict__ out, size_t pstride, float* __restrict__ se_sum, \
    const float* __restrict__ se_sums_in, \
    const float* __restrict__ se_w1, const float* __restrict__ se_b1, \
    const float* __restrict__ se_w2, const float* __restrict__ se_b2, \
    float inv_spatial
#define CONV_PASS in, wt, gamma, beta, out, pstride, se_sum, se_sums_in, \
    se_w1, se_b1, se_w2, se_b2, inv_spatial

__global__ __launch_bounds__(256) void conv1_k(CONV_ARGS) {
    conv_body<1, 1, 16, 16, 128, 128, 1, 128, 2, 2, 1, 256, true, true, 0, 1>(CONV_PASS);
}
// conv2: 4 waves x 8 couts, PPT=4 rows/thread, tile 4x64, CB=4, de-interleaved.
__global__ __launch_bounds__(256) void conv2_k(CONV_ARGS) {
    conv_ws_body<16, 16, 32, 8, 128, 64, 2, 64, 4, 4, 256, true, true, 1, 1>(CONV_PASS);
}
// conv3: 8 waves x 8 couts (512 thr), PPT=2, tile 4x32, CB=8, de-interleaved.
__global__ __launch_bounds__(512) void conv3_k(CONV_ARGS) {
    conv_ws_body<32, 32, 64, 8, 64, 32, 2, 32, 2, 8, 512, true, true, 2, 1>(CONV_PASS);
}
__global__ __launch_bounds__(256) void pc_k(CONV_ARGS) {
    conv_body<64, 16, 64, 16, 32, 16, 2, 16, 16, 1, 4, 256, false, false, 4, 4>(CONV_PASS);
}

// ---------------------------------------------------------------------------
// Fused squash + u_hat. Block = 256 capsules.
// ---------------------------------------------------------------------------
__global__ __launch_bounds__(256) void squash_uhat_k(
    const float* __restrict__ up, size_t pstride,
    const float* __restrict__ W, float* __restrict__ u_hat)
{
    const int base = blockIdx.x * 256;
    const int tid = threadIdx.x;
    __shared__ float ush[256][8];

    {
        const int cap = base + tid;
        const int b = cap >> 11, i = cap & 2047;
        const int chi = i >> 8, spx = i & 255;
        const size_t off = ((size_t)(b * 64 + chi * 8)) * 256 + spx;
        float s[8];
        float n2 = 0.0f;
#pragma unroll
        for (int j = 0; j < 8; j++) {
            const size_t o = off + (size_t)j * 256;
            s[j] = (up[o] + up[o + pstride]) + (up[o + 2 * pstride] + up[o + 3 * pstride]);
            n2 = fmaf(s[j], s[j], n2);
        }
        const float n = sqrtf(n2);
        const float f = (n2 / (1.0f + n2)) / (n + 1e-8f);
#pragma unroll
        for (int j = 0; j < 8; j++) ush[tid][j] = s[j] * f;
    }
    __syncthreads();

    float* ob = u_hat + (size_t)base * 48;
#pragma unroll 4
    for (int k = 0; k < 48; ++k) {
        int o = tid + k * 256;
        int c = o / 48, cd = o % 48;
        int gi = (base + c) & 2047;
        const float* wp = W + (size_t)gi * 384 + cd * 8;
        float a = 0.0f;
#pragma unroll
        for (int e = 0; e < 8; e++) a = fmaf(wp[e], ush[c][e], a);
        ob[o] = a;
    }
}

// ---------------------------------------------------------------------------
template <int IT>
__global__ __launch_bounds__(256) void sweep_k(const float* __restrict__ u_hat,
                                               const float* __restrict__ s_hist,
                                               float* __restrict__ s_out)
{
    const int b = blockIdx.y;
    const int i = blockIdx.x * 256 + threadIdx.x;
    const int tid = threadIdx.x;
    __shared__ float vsh[IT > 0 ? IT : 1][48];
    __shared__ float fac[IT > 0 ? IT : 1][3];
    __shared__ float red[4][48];

    const float4* qp = (const float4*)(u_hat + ((size_t)b * 2048 + i) * 48);
    float uhv[48];
#pragma unroll
    for (int q = 0; q < 12; ++q) {
        float4 t = qp[q];
        uhv[q * 4 + 0] = t.x; uhv[q * 4 + 1] = t.y;
        uhv[q * 4 + 2] = t.z; uhv[q * 4 + 3] = t.w;
    }

    if (IT > 0) {
        if (tid < IT * 48) {
            int t = tid / 48, c = tid % 48;
            vsh[t][c] = s_hist[((size_t)t * 64 + b) * 48 + c];
        }
        __syncthreads();
        if (tid < IT * 3) {
            int t = tid / 3, j = tid % 3;
            float n2 = 0.0f;
            for (int d = 0; d < 16; ++d) { float s = vsh[t][j * 16 + d]; n2 = fmaf(s, s, n2); }
            float n = sqrtf(n2);
            fac[t][j] = (n2 / (1.0f + n2)) / (n + 1e-8f);
        }
        __syncthreads();
        if (tid < IT * 48) {
            int t = tid / 48, c = tid % 48;
            vsh[t][c] *= fac[t][c / 16];
        }
        __syncthreads();
    }

    float c0, c1, c2;
    if (IT == 0) {
        c0 = c1 = c2 = (1.0f / 3.0f);
    } else {
        float b0 = 0.0f, b1 = 0.0f, b2 = 0.0f;
#pragma unroll
        for (int t = 0; t < IT; ++t)
#pragma unroll
            for (int d = 0; d < 16; ++d) {
                b0 = fmaf(uhv[d],      vsh[t][d],      b0);
                b1 = fmaf(uhv[16 + d], vsh[t][16 + d], b1);
                b2 = fmaf(uhv[32 + d], vsh[t][32 + d], b2);
            }
        float m = fmaxf(b0, fmaxf(b1, b2));
        float e0 = expf(b0 - m), e1 = expf(b1 - m), e2 = expf(b2 - m);
        float inv = 1.0f / (e0 + e1 + e2);
        c0 = e0 * inv; c1 = e1 * inv; c2 = e2 * inv;
    }

    float sp[48];
#pragma unroll
    for (int d = 0; d < 16; ++d) {
        sp[d]      = c0 * uhv[d];
        sp[16 + d] = c1 * uhv[16 + d];
        sp[32 + d] = c2 * uhv[32 + d];
    }
    const int lane = tid & 63, wv = tid >> 6;
#pragma unroll
    for (int j = 0; j < 48; ++j) {
        float x = sp[j];
        for (int off = 32; off; off >>= 1) x += __shfl_down(x, off, 64);
        if (lane == 0) red[wv][j] = x;
    }
    __syncthreads();
    if (tid < 48) {
        float x = red[0][tid] + red[1][tid] + red[2][tid] + red[3][tid];
        atomicAdd(&s_out[(size_t)b * 48 + tid], x);
    }
}

// ---------------------------------------------------------------------------
__global__ __launch_bounds__(64) void route_out_k(const float* __restrict__ s2,
                                                  float* __restrict__ out)
{
    const int b = blockIdx.x;
    __shared__ float s[48];
    if (threadIdx.x < 48) s[threadIdx.x] = s2[(size_t)b * 48 + threadIdx.x];
    __syncthreads();
    if (threadIdx.x < 3) {
        int j = threadIdx.x;
        float n2 = 0.0f;
        for (int d = 0; d < 16; ++d) { float v = s[j * 16 + d]; n2 = fmaf(v, v, n2); }
        float n = sqrtf(n2);
        float fc = (n2 / (1.0f + n2)) / (n + 1e-8f);
        out[b * 3 + j] = fc * n;
    }
}

// ---------------------------------------------------------------------------
extern "C" void kernel_launch(void* const* d_in, const int* in_sizes, int n_in,
                              void* d_out, int out_size, void* d_ws, size_t ws_size,
                              hipStream_t stream)
{
    const float* x       = (const float*)d_in[0];
    const float* conv1_w = (const float*)d_in[1];
    const float* bn1_g   = (const float*)d_in[2];
    const float* bn1_b   = (const float*)d_in[3];
    const float* se1_w1  = (const float*)d_in[4];
    const float* se1_b1  = (const float*)d_in[5];
    const float* se1_w2  = (const float*)d_in[6];
    const float* se1_b2  = (const float*)d_in[7];
    const float* conv2_w = (const float*)d_in[8];
    const float* bn2_g   = (const float*)d_in[9];
    const float* bn2_b   = (const float*)d_in[10];
    const float* se2_w1  = (const float*)d_in[11];
    const float* se2_b1  = (const float*)d_in[12];
    const float* se2_w2  = (const float*)d_in[13];
    const float* se2_b2  = (const float*)d_in[14];
    const float* conv3_w = (const float*)d_in[15];
    const float* bn3_g   = (const float*)d_in[16];
    const float* bn3_b   = (const float*)d_in[17];
    const float* se3_w1  = (const float*)d_in[18];
    const float* se3_b1  = (const float*)d_in[19];
    const float* se3_w2  = (const float*)d_in[20];
    const float* se3_b2  = (const float*)d_in[21];
    const float* pc_w    = (const float*)d_in[22];
    const float* pc_b    = (const float*)d_in[23];
    const float* W_digit = (const float*)d_in[24];  // (1,2048,3,16,8)

    float* ws = (float*)d_ws;
    float* h1     = ws;
    float* h2     = ws + 16777216;
    float* h3     = ws;                  // overlays dead h1 (conv3 writes here)
    float* uparts = ws + 4194304;
    float* u_hat  = ws + 9437184;
    float* sums   = ws + 25165824;
    float* s1 = sums, *s2 = sums + 1024, *s3 = sums + 3072;
    float* s_buf  = sums + 7168;
    float* w1t    = ws + 25182272;
    float* w2t    = w1t + 144;
    float* w3t    = w2t + 4608;
    float* wpt    = w3t + 18432;

    hipMemsetAsync(sums, 0, 16448 * sizeof(float), stream);
    wtrans_all_k<<<235, 256, 0, stream>>>(conv1_w, conv2_w, conv3_w, pc_w,
                                          w1t, w2t, w3t, wpt);

    // conv1: 1->16, 128x128, s1. 2048 blocks.
    conv1_k<<<dim3(32, 1, 64), 256, 0, stream>>>(
        x, w1t, bn1_g, bn1_b, h1, 0, s1,
        nullptr, nullptr, nullptr, nullptr, nullptr, 0.0f);

    // conv2: 16->32, ->64x64, s2. Wave-split 4x8 couts, PPT=4, CB=4. 1024 blocks.
    conv2_k<<<dim3(16, 1, 64), 256, 0, stream>>>(
        h1, w2t, bn2_g, bn2_b, h2, 0, s2,
        s1, se1_w1, se1_b1, se1_w2, se1_b2, 1.0f / 16384.0f);

    // conv3: 32->64, ->32x32, s2. Wave-split 8x8 couts (512 thr), PPT=2, CB=8,
    // BN+ReLU+SE3 fused. 512 blocks. Writes h3 (over dead h1).
    conv3_k<<<dim3(8, 1, 64), 512, 0, stream>>>(
        h2, w3t, bn3_g, bn3_b, h3, 0, s3,
        s2, se2_w1, se2_b1, se2_w2, se2_b2, 1.0f / 4096.0f);

    // primary caps: 64->64, ->16x16, s2, +bias. COB=16/NG=4, KSPLIT=4, CB=4.
    pc_k<<<dim3(1, 16, 64), 256, 0, stream>>>(
        h3, wpt, pc_b, nullptr, uparts, (size_t)1048576, nullptr,
        s3, se3_w1, se3_b1, se3_w2, se3_b2, 1.0f / 1024.0f);

    squash_uhat_k<<<512, 256, 0, stream>>>(uparts, (size_t)1048576, W_digit, u_hat);

    sweep_k<0><<<dim3(8, 64), 256, 0, stream>>>(u_hat, s_buf, s_buf + 0 * 64 * 48);
    sweep_k<1><<<dim3(8, 64), 256, 0, stream>>>(u_hat, s_buf, s_buf + 1 * 64 * 48);
    sweep_k<2><<<dim3(8, 64), 256, 0, stream>>>(u_hat, s_buf, s_buf + 2 * 64 * 48);
    route_out_k<<<64, 64, 0, stream>>>(s_buf + 2 * 64 * 48, (float*)d_out);
}

// Round 15
// 227.425 us; speedup vs baseline: 1.0015x; 1.0015x over previous
//
#include <hip/hip_runtime.h>
#include <math.h>

#define BN_INV_F 0.9999950000374997f

__device__ __forceinline__ void gload_lds4(const float* g, float* l) {
    __builtin_amdgcn_global_load_lds(
        (const __attribute__((address_space(1))) void*)g,
        (__attribute__((address_space(3))) void*)l, 4, 0, 0);
}
__device__ __forceinline__ void gload_lds16(const float* g, float* l) {
    __builtin_amdgcn_global_load_lds(
        (const __attribute__((address_space(1))) void*)g,
        (__attribute__((address_space(3))) void*)l, 16, 0, 0);
}

// ---------------------------------------------------------------------------
// Weight transpose (once): wt[(cin*9+k)*COUT + co] = w[co][cin][k]
// ---------------------------------------------------------------------------
__global__ __launch_bounds__(256) void wtrans_all_k(
    const float* __restrict__ w1, const float* __restrict__ w2,
    const float* __restrict__ w3, const float* __restrict__ wp,
    float* __restrict__ w1t, float* __restrict__ w2t,
    float* __restrict__ w3t, float* __restrict__ wpt)
{
    int i = blockIdx.x * 256 + threadIdx.x;
    if (i < 144) {
        int co = i % 16, k = i / 16;
        w1t[i] = w1[co * 9 + k];
    } else if (i < 4752) {
        int t = i - 144;
        int co = t % 32, rk = t / 32, cin = rk / 9, k = rk % 9;
        w2t[t] = w2[(co * 16 + cin) * 9 + k];
    } else if (i < 23184) {
        int t = i - 4752;
        int co = t % 64, rk = t / 64, cin = rk / 9, k = rk % 9;
        w3t[t] = w3[(co * 32 + cin) * 9 + k];
    } else if (i < 60048) {
        int t = i - 23184;
        int co = t % 64, rk = t / 64, cin = rk / 9, k = rk % 9;
        wpt[t] = wp[(co * 64 + cin) * 9 + k];
    }
}

// ---------------------------------------------------------------------------
// Original conv body (conv1 / pc): thread-split couts (COB per thread).
// ---------------------------------------------------------------------------
template <int CIN, int CINB, int COUT, int COB, int HIN, int HOUT, int STRIDE,
          int TW, int ROWS_T, int PPT, int CB, int NTHREADS,
          bool BN_RELU, bool SE_SUM, int HSE_IN, int KSPLIT>
__device__ __forceinline__ void conv_body(
    const float* __restrict__ in, const float* __restrict__ wt,
    const float* __restrict__ gamma, const float* __restrict__ beta,
    float* __restrict__ out, size_t pstride,
    float* __restrict__ se_sum, const float* __restrict__ se_sums_in,
    const float* __restrict__ se_w1, const float* __restrict__ se_b1,
    const float* __restrict__ se_w2, const float* __restrict__ se_b2,
    float inv_spatial)
{
    constexpr int WIN = HIN, WOUT = HOUT;
    constexpr int TH = ROWS_T * PPT;
    constexpr int IH_T = (TH - 1) * STRIDE + 3;
    constexpr int NW = NTHREADS / 64;
    constexpr int NCHUNK = CINB / CB;
    constexpr int SEGS = (WIN >= 64) ? (WIN / 64) : 1;
    constexpr int PAIRS = (IH_T + 1) / 2;
    constexpr int NG = COUT / COB;
    constexpr int IHW = IH_T * WIN;
    constexpr int CHUNK_BYTES = CB * IHW * 4;
    constexpr bool FAST16 = (CHUNK_BYTES % 1024) == 0;
    constexpr int NISS = CHUNK_BYTES / 1024;
    static_assert(NTHREADS == TW * ROWS_T, "geometry");
    static_assert(TW == WOUT, "tile must span full output width");
    static_assert(CINB % CB == 0, "chunking");
    static_assert(WIN % 64 == 0 || WIN == 32, "stage width");

    const int b = blockIdx.z;
    const int gy = blockIdx.y;
    const int ty = blockIdx.x;
    const int tid = threadIdx.x;
    const int wo = tid % TW;
    const int rg = tid / TW;
    const int g = gy % NG;
    const int kk = gy / NG;
    const int cin0 = kk * CINB;

    __shared__ float in_t[2][CB * IH_T * WIN];
    __shared__ float scl[CIN];
    __shared__ float gl[COB], bl[COB];
    __shared__ float red[NW][COB];
    __shared__ float hid[HSE_IN > 0 ? HSE_IN : 1];

    const float* inb = in + (size_t)b * CIN * HIN * WIN;
    const int gr0 = ty * TH * STRIDE - 1;
    const int wos = wo * STRIDE;
    const int wvid = tid >> 6, lane = tid & 63;
    const bool interior = (gr0 >= 0) && (gr0 + IH_T <= HIN);

    auto stage = [&](int c, int buf) {
        const int cb0 = cin0 + c * CB;
        float* bb = &in_t[buf][0];
        if (FAST16 && interior) {
            for (int i = wvid; i < NISS; i += NW) {
                int fe = i * 256 + lane * 4;
                int ci = fe / IHW;
                int rem = fe - ci * IHW;
                int lr = rem / WIN;
                int lc = rem - lr * WIN;
                const float* gsrc = inb + (size_t)(cb0 + ci) * (HIN * WIN)
                                  + (size_t)(gr0 + lr) * WIN + lc;
                gload_lds16(gsrc, bb + i * 256);
            }
        } else if (WIN >= 64) {
            for (int r = wvid; r < CB * IH_T; r += NW) {
                int ci = r / IH_T, lr = r - ci * IH_T;
                int gr = gr0 + lr;
                float* ldst = bb + (ci * IH_T + lr) * WIN;
                if (gr >= 0 && gr < HIN) {
                    const float* gsrc = inb + (size_t)(cb0 + ci) * HIN * WIN + (size_t)gr * WIN;
#pragma unroll
                    for (int s = 0; s < SEGS; ++s)
                        gload_lds4(gsrc + s * 64 + lane, ldst + s * 64);
                } else {
#pragma unroll
                    for (int s = 0; s < SEGS; ++s) ldst[s * 64 + lane] = 0.0f;
                }
            }
        } else {
            for (int pz = wvid; pz < CB * PAIRS; pz += NW) {
                int ci = pz / PAIRS, q = pz - ci * PAIRS;
                int lr0 = q * 2;
                int nr = (lr0 + 1 < IH_T) ? 2 : 1;
                int grr = gr0 + lr0;
                float* ldst = bb + (ci * IH_T + lr0) * WIN;
                if (nr == 2 && grr >= 0 && grr + 1 < HIN) {
                    const float* gsrc = inb + (size_t)(cb0 + ci) * HIN * WIN + (size_t)grr * WIN + lane;
                    gload_lds4(gsrc, ldst);
                } else {
                    for (int e = lane; e < nr * WIN; e += 64) {
                        int rr = e / WIN, cc = e - rr * WIN;
                        int gr = grr + rr;
                        ldst[e] = (gr >= 0 && gr < HIN)
                            ? inb[(size_t)(cb0 + ci) * HIN * WIN + (size_t)gr * WIN + cc] : 0.0f;
                    }
                }
            }
        }
    };

    stage(0, 0);

    if (HSE_IN > 0) {
        if (tid < HSE_IN) {
            float a = se_b1[tid];
            for (int c = 0; c < CIN; ++c)
                a = fmaf(se_sums_in[b * CIN + c] * inv_spatial, se_w1[tid * CIN + c], a);
            hid[tid] = fmaxf(a, 0.0f);
        }
        __syncthreads();
        if (tid < CIN) {
            float a = se_b2[tid];
            for (int h = 0; h < HSE_IN; ++h)
                a = fmaf(hid[h], se_w2[tid * HSE_IN + h], a);
            scl[tid] = 1.0f / (1.0f + expf(-a));
        }
    } else {
        for (int t = tid; t < CIN; t += NTHREADS) scl[t] = 1.0f;
    }
    if (tid < COB) {
        int co = g * COB + tid;
        if (BN_RELU) {
            gl[tid] = gamma[co] * BN_INV_F;
            bl[tid] = beta[co];
        } else {
            gl[tid] = (kk == 0) ? gamma[co] : 0.0f;
        }
    }

    float acc[PPT][COB];
#pragma unroll
    for (int p = 0; p < PPT; ++p)
#pragma unroll
        for (int co = 0; co < COB; ++co) acc[p][co] = 0.0f;

    int cur = 0;
    for (int c = 0; c < NCHUNK; ++c) {
        asm volatile("s_waitcnt vmcnt(0)" ::: "memory");
        __syncthreads();
        if (c + 1 < NCHUNK) stage(c + 1, cur ^ 1);

        const float* bb = &in_t[cur][0];
#pragma unroll
        for (int ci = 0; ci < CB; ++ci) {
            const int cw = cin0 + c * CB + ci;
            const float sc = scl[cw];
            const float* wtap = wt + (size_t)cw * 9 * COUT + g * COB;
            const float* bb_ci = bb + ci * IH_T * WIN;
#pragma unroll
            for (int kh = 0; kh < 3; ++kh) {
#pragma unroll
                for (int kw = 0; kw < 3; ++kw) {
                    const float* wrow = wtap + (kh * 3 + kw) * COUT;
#pragma unroll
                    for (int p = 0; p < PPT; ++p) {
                        const float* row = bb_ci + ((rg + p * ROWS_T) * STRIDE + kh) * WIN;
                        int wi = wos + kw - 1;
                        float v;
                        if (kw == 0) {
                            v = row[wi < 0 ? 0 : wi];
                            if (wi < 0) v = 0.0f;
                        } else if (STRIDE == 1 && kw == 2) {
                            v = row[wi >= WIN ? WIN - 1 : wi];
                            if (wi >= WIN) v = 0.0f;
                        } else {
                            v = row[wi];
                        }
                        v *= sc;
#pragma unroll
                        for (int co = 0; co < COB; ++co)
                            acc[p][co] = fmaf(wrow[co], v, acc[p][co]);
                    }
                }
            }
        }
        cur ^= 1;
    }

    float tsum[COB];
#pragma unroll
    for (int co = 0; co < COB; ++co) tsum[co] = 0.0f;
    float* ob = out + (size_t)kk * pstride
              + ((size_t)b * COUT + (size_t)g * COB) * HOUT * WOUT;
#pragma unroll
    for (int p = 0; p < PPT; ++p) {
        const int ho = ty * TH + rg + p * ROWS_T;
#pragma unroll
        for (int co = 0; co < COB; ++co) {
            float v;
            if (BN_RELU)
                v = fmaxf(fmaf(acc[p][co], gl[co], bl[co]), 0.0f);
            else
                v = acc[p][co] + gl[co];
            ob[(size_t)co * HOUT * WOUT + ho * WOUT + wo] = v;
            tsum[co] += v;
        }
    }

    if (SE_SUM) {
#pragma unroll
        for (int co = 0; co < COB; ++co) {
            float v = tsum[co];
            for (int off = 32; off; off >>= 1) v += __shfl_down(v, off, 64);
            if (lane == 0) red[wvid][co] = v;
        }
        __syncthreads();
        if (tid < COB) {
            float v = 0.0f;
#pragma unroll
            for (int k = 0; k < NW; ++k) v += red[k][tid];
            atomicAdd(&se_sum[b * COUT + g * COB + tid], v);
        }
    }
}

// ---------------------------------------------------------------------------
// Wave-split conv body (conv2 / conv3), STRIDE==2 only. Each WAVE owns WCO
// couts over the whole tile. Input staged DE-INTERLEAVED per row:
// [even cols | odd cols] so stride-2 reads are unit-stride (bank-conflict-free).
// ---------------------------------------------------------------------------
template <int CIN, int CINB, int COUT, int WCO, int HIN, int HOUT, int STRIDE,
          int TW, int PPT, int CB, int NTHREADS,
          bool BN_RELU, bool SE_SUM, int HSE_IN, int KSPLIT>
__device__ __forceinline__ void conv_ws_body(
    const float* __restrict__ in, const float* __restrict__ wt,
    const float* __restrict__ gamma, const float* __restrict__ beta,
    float* __restrict__ out, size_t pstride,
    float* __restrict__ se_sum, const float* __restrict__ se_sums_in,
    const float* __restrict__ se_w1, const float* __restrict__ se_b1,
    const float* __restrict__ se_w2, const float* __restrict__ se_b2,
    float inv_spatial)
{
    constexpr int WIN = HIN, WOUT = HOUT;
    constexpr int NW = NTHREADS / 64;
    constexpr int WROWS = 64 / TW;
    constexpr int TH = WROWS * PPT;
    constexpr int IH_T = (TH - 1) * STRIDE + 3;
    constexpr int COBT = NW * WCO;
    constexpr int NG = COUT / COBT;
    constexpr int NCHUNK = CINB / CB;
    constexpr int SEGS = WIN / 64;
    constexpr int HALF = WIN / 2;
    static_assert(STRIDE == 2, "wave-split body is stride-2 only");
    static_assert(TW == WOUT, "tile spans full width");
    static_assert(CINB % CB == 0, "chunking");
    static_assert(WIN % 64 == 0, "stage width");
    static_assert(COUT % COBT == 0, "cout split");

    const int b = blockIdx.z;
    const int gy = blockIdx.y;
    const int ty = blockIdx.x;
    const int tid = threadIdx.x;
    const int lane = tid & 63;
    const int wvu = __builtin_amdgcn_readfirstlane(tid >> 6);
    const int wo = lane % TW;
    const int rl = lane / TW;
    const int g = gy % NG;
    const int kk = gy / NG;
    const int cin0 = kk * CINB;

    __shared__ float in_t[2][CB * IH_T * WIN];
    __shared__ float scl[CIN];
    __shared__ float gl[COBT], bl[COBT];
    __shared__ float red[NW][WCO];
    __shared__ float hid[HSE_IN > 0 ? HSE_IN : 1];

    const float* inb = in + (size_t)b * CIN * HIN * WIN;
    const int gr0 = ty * TH * STRIDE - 1;

    // de-interleaved staging: LDS row = [E(HALF) | O(HALF)]; 4B DMA, per-lane src
    auto stage = [&](int c, int buf) {
        const int cb0 = cin0 + c * CB;
        float* bb = &in_t[buf][0];
        for (int r = wvu; r < CB * IH_T; r += NW) {
            int ci = r / IH_T, lr = r - ci * IH_T;
            int gr = gr0 + lr;
            float* ldst = bb + (ci * IH_T + lr) * WIN;
            if (gr >= 0 && gr < HIN) {
                const float* gsrc = inb + (size_t)(cb0 + ci) * HIN * WIN + (size_t)gr * WIN;
#pragma unroll
                for (int s = 0; s < SEGS; ++s) {
                    int p = s * 64 + lane;
                    int half = p / HALF;
                    int idx = p - half * HALF;
                    gload_lds4(gsrc + 2 * idx + half, ldst + s * 64);
                }
            } else {
#pragma unroll
                for (int s = 0; s < SEGS; ++s) ldst[s * 64 + lane] = 0.0f;
            }
        }
    };

    stage(0, 0);

    if (HSE_IN > 0) {
        if (tid < HSE_IN) {
            float a = se_b1[tid];
            for (int c = 0; c < CIN; ++c)
                a = fmaf(se_sums_in[b * CIN + c] * inv_spatial, se_w1[tid * CIN + c], a);
            hid[tid] = fmaxf(a, 0.0f);
        }
        __syncthreads();
        if (tid < CIN) {
            float a = se_b2[tid];
            for (int h = 0; h < HSE_IN; ++h)
                a = fmaf(hid[h], se_w2[tid * HSE_IN + h], a);
            scl[tid] = 1.0f / (1.0f + expf(-a));
        }
    } else {
        for (int t = tid; t < CIN; t += NTHREADS) scl[t] = 1.0f;
    }
    if (tid < COBT) {
        int co = g * COBT + tid;
        if (BN_RELU) {
            gl[tid] = gamma[co] * BN_INV_F;
            bl[tid] = beta[co];
        } else {
            gl[tid] = (kk == 0) ? gamma[co] : 0.0f;
        }
    }

    float acc[PPT][WCO];
#pragma unroll
    for (int p = 0; p < PPT; ++p)
#pragma unroll
        for (int co = 0; co < WCO; ++co) acc[p][co] = 0.0f;

    int cur = 0;
    for (int c = 0; c < NCHUNK; ++c) {
        asm volatile("s_waitcnt vmcnt(0)" ::: "memory");
        __syncthreads();
        if (c + 1 < NCHUNK) stage(c + 1, cur ^ 1);

        const float* bb = &in_t[cur][0];
#pragma unroll
        for (int ci = 0; ci < CB; ++ci) {
            const int cw = cin0 + c * CB + ci;
            const float sc = scl[cw];
            const float* wtap = wt + (size_t)cw * 9 * COUT + g * COBT + wvu * WCO;
            const float* bb_ci = bb + ci * IH_T * WIN;
#pragma unroll
            for (int kh = 0; kh < 3; ++kh) {
                float iwv[PPT][3];
#pragma unroll
                for (int p = 0; p < PPT; ++p) {
                    const float* row = bb_ci + ((rl + p * WROWS) * STRIDE + kh) * WIN;
                    float e  = row[wo];
                    float om = row[HALF + ((wo == 0) ? 0 : wo - 1)];
                    if (wo == 0) om = 0.0f;
                    float op = row[HALF + wo];
                    iwv[p][0] = om * sc;
                    iwv[p][1] = e * sc;
                    iwv[p][2] = op * sc;
                }
#pragma unroll
                for (int kw = 0; kw < 3; ++kw) {
                    const float* wrow = wtap + (kh * 3 + kw) * COUT;  // uniform -> SGPR
#pragma unroll
                    for (int p = 0; p < PPT; ++p) {
                        const float v = iwv[p][kw];
#pragma unroll
                        for (int co = 0; co < WCO; ++co)
                            acc[p][co] = fmaf(wrow[co], v, acc[p][co]);
                    }
                }
            }
        }
        cur ^= 1;
    }

    float tsum[WCO];
#pragma unroll
    for (int co = 0; co < WCO; ++co) tsum[co] = 0.0f;
    float* ob = out + (size_t)kk * pstride
              + ((size_t)b * COUT + (size_t)g * COBT + (size_t)wvu * WCO) * HOUT * WOUT;
#pragma unroll
    for (int p = 0; p < PPT; ++p) {
        const int ho = ty * TH + rl + p * WROWS;
#pragma unroll
        for (int co = 0; co < WCO; ++co) {
            float v;
            if (BN_RELU)
                v = fmaxf(fmaf(acc[p][co], gl[wvu * WCO + co], bl[wvu * WCO + co]), 0.0f);
            else
                v = acc[p][co] + gl[wvu * WCO + co];
            ob[(size_t)co * HOUT * WOUT + ho * WOUT + wo] = v;
            tsum[co] += v;
        }
    }

    if (SE_SUM) {
#pragma unroll
        for (int co = 0; co < WCO; ++co) {
            float v = tsum[co];
            for (int off = 32; off; off >>= 1) v += __shfl_down(v, off, 64);
            if (lane == 0) red[wvu][co] = v;
        }
        __syncthreads();
        if (lane < WCO)
            atomicAdd(&se_sum[b * COUT + g * COBT + wvu * WCO + lane], red[wvu][lane]);
    }
}

#define CONV_ARGS \
    const float* __restrict__ in, const float* __restrict__ wt, \
    const float* __restrict__ gamma, const float* __restrict__ beta, \
    float* __restrict__ out, size_t pstride, float* __restrict__ se_sum, \
    const float* __restrict__ se_sums_in, \
    const float* __restrict__ se_w1, const float* __restrict__ se_b1, \
    const float* __restrict__ se_w2, const float* __restrict__ se_b2, \
    float inv_spatial
#define CONV_PASS in, wt, gamma, beta, out, pstride, se_sum, se_sums_in, \
    se_w1, se_b1, se_w2, se_b2, inv_spatial

__global__ __launch_bounds__(256) void conv1_k(CONV_ARGS) {
    conv_body<1, 1, 16, 16, 128, 128, 1, 128, 2, 2, 1, 256, true, true, 0, 1>(CONV_PASS);
}
// conv2: 4 waves x 8 couts, PPT=2 (TH=2, IH_T=5), CB=4, LDS 20.5 KB. 2048 blocks.
__global__ __launch_bounds__(256) void conv2_k(CONV_ARGS) {
    conv_ws_body<16, 16, 32, 8, 128, 64, 2, 64, 2, 4, 256, true, true, 1, 1>(CONV_PASS);
}
// conv3: 8 waves x 8 couts (512 thr), PPT=1 (TH=2, IH_T=5), CB=8, LDS 20.5 KB. 1024 blocks.
__global__ __launch_bounds__(512) void conv3_k(CONV_ARGS) {
    conv_ws_body<32, 32, 64, 8, 64, 32, 2, 32, 1, 8, 512, true, true, 2, 1>(CONV_PASS);
}
__global__ __launch_bounds__(256) void pc_k(CONV_ARGS) {
    conv_body<64, 16, 64, 16, 32, 16, 2, 16, 16, 1, 4, 256, false, false, 4, 4>(CONV_PASS);
}

// ---------------------------------------------------------------------------
// Fused squash + u_hat. Block = 256 capsules.
// ---------------------------------------------------------------------------
__global__ __launch_bounds__(256) void squash_uhat_k(
    const float* __restrict__ up, size_t pstride,
    const float* __restrict__ W, float* __restrict__ u_hat)
{
    const int base = blockIdx.x * 256;
    const int tid = threadIdx.x;
    __shared__ float ush[256][8];

    {
        const int cap = base + tid;
        const int b = cap >> 11, i = cap & 2047;
        const int chi = i >> 8, spx = i & 255;
        const size_t off = ((size_t)(b * 64 + chi * 8)) * 256 + spx;
        float s[8];
        float n2 = 0.0f;
#pragma unroll
        for (int j = 0; j < 8; j++) {
            const size_t o = off + (size_t)j * 256;
            s[j] = (up[o] + up[o + pstride]) + (up[o + 2 * pstride] + up[o + 3 * pstride]);
            n2 = fmaf(s[j], s[j], n2);
        }
        const float n = sqrtf(n2);
        const float f = (n2 / (1.0f + n2)) / (n + 1e-8f);
#pragma unroll
        for (int j = 0; j < 8; j++) ush[tid][j] = s[j] * f;
    }
    __syncthreads();

    float* ob = u_hat + (size_t)base * 48;
#pragma unroll 4
    for (int k = 0; k < 48; ++k) {
        int o = tid + k * 256;
        int c = o / 48, cd = o % 48;
        int gi = (base + c) & 2047;
        const float* wp = W + (size_t)gi * 384 + cd * 8;
        float a = 0.0f;
#pragma unroll
        for (int e = 0; e < 8; e++) a = fmaf(wp[e], ush[c][e], a);
        ob[o] = a;
    }
}

// ---------------------------------------------------------------------------
template <int IT>
__global__ __launch_bounds__(256) void sweep_k(const float* __restrict__ u_hat,
                                               const float* __restrict__ s_hist,
                                               float* __restrict__ s_out)
{
    const int b = blockIdx.y;
    const int i = blockIdx.x * 256 + threadIdx.x;
    const int tid = threadIdx.x;
    __shared__ float vsh[IT > 0 ? IT : 1][48];
    __shared__ float fac[IT > 0 ? IT : 1][3];
    __shared__ float red[4][48];

    const float4* qp = (const float4*)(u_hat + ((size_t)b * 2048 + i) * 48);
    float uhv[48];
#pragma unroll
    for (int q = 0; q < 12; ++q) {
        float4 t = qp[q];
        uhv[q * 4 + 0] = t.x; uhv[q * 4 + 1] = t.y;
        uhv[q * 4 + 2] = t.z; uhv[q * 4 + 3] = t.w;
    }

    if (IT > 0) {
        if (tid < IT * 48) {
            int t = tid / 48, c = tid % 48;
            vsh[t][c] = s_hist[((size_t)t * 64 + b) * 48 + c];
        }
        __syncthreads();
        if (tid < IT * 3) {
            int t = tid / 3, j = tid % 3;
            float n2 = 0.0f;
            for (int d = 0; d < 16; ++d) { float s = vsh[t][j * 16 + d]; n2 = fmaf(s, s, n2); }
            float n = sqrtf(n2);
            fac[t][j] = (n2 / (1.0f + n2)) / (n + 1e-8f);
        }
        __syncthreads();
        if (tid < IT * 48) {
            int t = tid / 48, c = tid % 48;
            vsh[t][c] *= fac[t][c / 16];
        }
        __syncthreads();
    }

    float c0, c1, c2;
    if (IT == 0) {
        c0 = c1 = c2 = (1.0f / 3.0f);
    } else {
        float b0 = 0.0f, b1 = 0.0f, b2 = 0.0f;
#pragma unroll
        for (int t = 0; t < IT; ++t)
#pragma unroll
            for (int d = 0; d < 16; ++d) {
                b0 = fmaf(uhv[d],      vsh[t][d],      b0);
                b1 = fmaf(uhv[16 + d], vsh[t][16 + d], b1);
                b2 = fmaf(uhv[32 + d], vsh[t][32 + d], b2);
            }
        float m = fmaxf(b0, fmaxf(b1, b2));
        float e0 = expf(b0 - m), e1 = expf(b1 - m), e2 = expf(b2 - m);
        float inv = 1.0f / (e0 + e1 + e2);
        c0 = e0 * inv; c1 = e1 * inv; c2 = e2 * inv;
    }

    float sp[48];
#pragma unroll
    for (int d = 0; d < 16; ++d) {
        sp[d]      = c0 * uhv[d];
        sp[16 + d] = c1 * uhv[16 + d];
        sp[32 + d] = c2 * uhv[32 + d];
    }
    const int lane = tid & 63, wv = tid >> 6;
#pragma unroll
    for (int j = 0; j < 48; ++j) {
        float x = sp[j];
        for (int off = 32; off; off >>= 1) x += __shfl_down(x, off, 64);
        if (lane == 0) red[wv][j] = x;
    }
    __syncthreads();
    if (tid < 48) {
        float x = red[0][tid] + red[1][tid] + red[2][tid] + red[3][tid];
        atomicAdd(&s_out[(size_t)b * 48 + tid], x);
    }
}

// ---------------------------------------------------------------------------
__global__ __launch_bounds__(64) void route_out_k(const float* __restrict__ s2,
                                                  float* __restrict__ out)
{
    const int b = blockIdx.x;
    __shared__ float s[48];
    if (threadIdx.x < 48) s[threadIdx.x] = s2[(size_t)b * 48 + threadIdx.x];
    __syncthreads();
    if (threadIdx.x < 3) {
        int j = threadIdx.x;
        float n2 = 0.0f;
        for (int d = 0; d < 16; ++d) { float v = s[j * 16 + d]; n2 = fmaf(v, v, n2); }
        float n = sqrtf(n2);
        float fc = (n2 / (1.0f + n2)) / (n + 1e-8f);
        out[b * 3 + j] = fc * n;
    }
}

// ---------------------------------------------------------------------------
extern "C" void kernel_launch(void* const* d_in, const int* in_sizes, int n_in,
                              void* d_out, int out_size, void* d_ws, size_t ws_size,
                              hipStream_t stream)
{
    const float* x       = (const float*)d_in[0];
    const float* conv1_w = (const float*)d_in[1];
    const float* bn1_g   = (const float*)d_in[2];
    const float* bn1_b   = (const float*)d_in[3];
    const float* se1_w1  = (const float*)d_in[4];
    const float* se1_b1  = (const float*)d_in[5];
    const float* se1_w2  = (const float*)d_in[6];
    const float* se1_b2  = (const float*)d_in[7];
    const float* conv2_w = (const float*)d_in[8];
    const float* bn2_g   = (const float*)d_in[9];
    const float* bn2_b   = (const float*)d_in[10];
    const float* se2_w1  = (const float*)d_in[11];
    const float* se2_b1  = (const float*)d_in[12];
    const float* se2_w2  = (const float*)d_in[13];
    const float* se2_b2  = (const float*)d_in[14];
    const float* conv3_w = (const float*)d_in[15];
    const float* bn3_g   = (const float*)d_in[16];
    const float* bn3_b   = (const float*)d_in[17];
    const float* se3_w1  = (const float*)d_in[18];
    const float* se3_b1  = (const float*)d_in[19];
    const float* se3_w2  = (const float*)d_in[20];
    const float* se3_b2  = (const float*)d_in[21];
    const float* pc_w    = (const float*)d_in[22];
    const float* pc_b    = (const float*)d_in[23];
    const float* W_digit = (const float*)d_in[24];  // (1,2048,3,16,8)

    float* ws = (float*)d_ws;
    float* h1     = ws;
    float* h2     = ws + 16777216;
    float* h3     = ws;                  // overlays dead h1 (conv3 writes here)
    float* uparts = ws + 4194304;
    float* u_hat  = ws + 9437184;
    float* sums   = ws + 25165824;
    float* s1 = sums, *s2 = sums + 1024, *s3 = sums + 3072;
    float* s_buf  = sums + 7168;
    float* w1t    = ws + 25182272;
    float* w2t    = w1t + 144;
    float* w3t    = w2t + 4608;
    float* wpt    = w3t + 18432;

    hipMemsetAsync(sums, 0, 16448 * sizeof(float), stream);
    wtrans_all_k<<<235, 256, 0, stream>>>(conv1_w, conv2_w, conv3_w, pc_w,
                                          w1t, w2t, w3t, wpt);

    // conv1: 1->16, 128x128, s1. 2048 blocks.
    conv1_k<<<dim3(32, 1, 64), 256, 0, stream>>>(
        x, w1t, bn1_g, bn1_b, h1, 0, s1,
        nullptr, nullptr, nullptr, nullptr, nullptr, 0.0f);

    // conv2: 16->32, ->64x64, s2. Wave-split 4x8, PPT=2 (TH=2). 2048 blocks.
    conv2_k<<<dim3(32, 1, 64), 256, 0, stream>>>(
        h1, w2t, bn2_g, bn2_b, h2, 0, s2,
        s1, se1_w1, se1_b1, se1_w2, se1_b2, 1.0f / 16384.0f);

    // conv3: 32->64, ->32x32, s2. Wave-split 8x8 (512 thr), PPT=1 (TH=2). 1024 blocks.
    conv3_k<<<dim3(16, 1, 64), 512, 0, stream>>>(
        h2, w3t, bn3_g, bn3_b, h3, 0, s3,
        s2, se2_w1, se2_b1, se2_w2, se2_b2, 1.0f / 4096.0f);

    // primary caps: 64->64, ->16x16, s2, +bias. COB=16/NG=4, KSPLIT=4, CB=4.
    pc_k<<<dim3(1, 16, 64), 256, 0, stream>>>(
        h3, wpt, pc_b, nullptr, uparts, (size_t)1048576, nullptr,
        s3, se3_w1, se3_b1, se3_w2, se3_b2, 1.0f / 1024.0f);

    squash_uhat_k<<<512, 256, 0, stream>>>(uparts, (size_t)1048576, W_digit, u_hat);

    sweep_k<0><<<dim3(8, 64), 256, 0, stream>>>(u_hat, s_buf, s_buf + 0 * 64 * 48);
    sweep_k<1><<<dim3(8, 64), 256, 0, stream>>>(u_hat, s_buf, s_buf + 1 * 64 * 48);
    sweep_k<2><<<dim3(8, 64), 256, 0, stream>>>(u_hat, s_buf, s_buf + 2 * 64 * 48);
    route_out_k<<<64, 64, 0, stream>>>(s_buf + 2 * 64 * 48, (float*)d_out);
}

// Round 16
// 224.565 us; speedup vs baseline: 1.0142x; 1.0127x over previous
//
#include <hip/hip_runtime.h>
#include <math.h>

#define BN_INV_F 0.9999950000374997f

__device__ __forceinline__ void gload_lds4(const float* g, float* l) {
    __builtin_amdgcn_global_load_lds(
        (const __attribute__((address_space(1))) void*)g,
        (__attribute__((address_space(3))) void*)l, 4, 0, 0);
}
__device__ __forceinline__ void gload_lds16(const float* g, float* l) {
    __builtin_amdgcn_global_load_lds(
        (const __attribute__((address_space(1))) void*)g,
        (__attribute__((address_space(3))) void*)l, 16, 0, 0);
}

// ---------------------------------------------------------------------------
// Weight transpose (once): wt[(cin*9+k)*COUT + co] = w[co][cin][k]
// ---------------------------------------------------------------------------
__global__ __launch_bounds__(256) void wtrans_all_k(
    const float* __restrict__ w1, const float* __restrict__ w2,
    const float* __restrict__ w3, const float* __restrict__ wp,
    float* __restrict__ w1t, float* __restrict__ w2t,
    float* __restrict__ w3t, float* __restrict__ wpt)
{
    int i = blockIdx.x * 256 + threadIdx.x;
    if (i < 144) {
        int co = i % 16, k = i / 16;
        w1t[i] = w1[co * 9 + k];
    } else if (i < 4752) {
        int t = i - 144;
        int co = t % 32, rk = t / 32, cin = rk / 9, k = rk % 9;
        w2t[t] = w2[(co * 16 + cin) * 9 + k];
    } else if (i < 23184) {
        int t = i - 4752;
        int co = t % 64, rk = t / 64, cin = rk / 9, k = rk % 9;
        w3t[t] = w3[(co * 32 + cin) * 9 + k];
    } else if (i < 60048) {
        int t = i - 23184;
        int co = t % 64, rk = t / 64, cin = rk / 9, k = rk % 9;
        wpt[t] = wp[(co * 64 + cin) * 9 + k];
    }
}

// ---------------------------------------------------------------------------
// Original conv body (conv1 / pc): thread-split couts, 2-buffer drain scheme.
// ---------------------------------------------------------------------------
template <int CIN, int CINB, int COUT, int COB, int HIN, int HOUT, int STRIDE,
          int TW, int ROWS_T, int PPT, int CB, int NTHREADS,
          bool BN_RELU, bool SE_SUM, int HSE_IN, int KSPLIT>
__device__ __forceinline__ void conv_body(
    const float* __restrict__ in, const float* __restrict__ wt,
    const float* __restrict__ gamma, const float* __restrict__ beta,
    float* __restrict__ out, size_t pstride,
    float* __restrict__ se_sum, const float* __restrict__ se_sums_in,
    const float* __restrict__ se_w1, const float* __restrict__ se_b1,
    const float* __restrict__ se_w2, const float* __restrict__ se_b2,
    float inv_spatial)
{
    constexpr int WIN = HIN, WOUT = HOUT;
    constexpr int TH = ROWS_T * PPT;
    constexpr int IH_T = (TH - 1) * STRIDE + 3;
    constexpr int NW = NTHREADS / 64;
    constexpr int NCHUNK = CINB / CB;
    constexpr int SEGS = (WIN >= 64) ? (WIN / 64) : 1;
    constexpr int PAIRS = (IH_T + 1) / 2;
    constexpr int NG = COUT / COB;
    constexpr int IHW = IH_T * WIN;
    constexpr int CHUNK_BYTES = CB * IHW * 4;
    constexpr bool FAST16 = (CHUNK_BYTES % 1024) == 0;
    constexpr int NISS = CHUNK_BYTES / 1024;
    static_assert(NTHREADS == TW * ROWS_T, "geometry");
    static_assert(TW == WOUT, "tile must span full output width");
    static_assert(CINB % CB == 0, "chunking");
    static_assert(WIN % 64 == 0 || WIN == 32, "stage width");

    const int b = blockIdx.z;
    const int gy = blockIdx.y;
    const int ty = blockIdx.x;
    const int tid = threadIdx.x;
    const int wo = tid % TW;
    const int rg = tid / TW;
    const int g = gy % NG;
    const int kk = gy / NG;
    const int cin0 = kk * CINB;

    __shared__ float in_t[2][CB * IH_T * WIN];
    __shared__ float scl[CIN];
    __shared__ float gl[COB], bl[COB];
    __shared__ float red[NW][COB];
    __shared__ float hid[HSE_IN > 0 ? HSE_IN : 1];

    const float* inb = in + (size_t)b * CIN * HIN * WIN;
    const int gr0 = ty * TH * STRIDE - 1;
    const int wos = wo * STRIDE;
    const int wvid = tid >> 6, lane = tid & 63;
    const bool interior = (gr0 >= 0) && (gr0 + IH_T <= HIN);

    auto stage = [&](int c, int buf) {
        const int cb0 = cin0 + c * CB;
        float* bb = &in_t[buf][0];
        if (FAST16 && interior) {
            for (int i = wvid; i < NISS; i += NW) {
                int fe = i * 256 + lane * 4;
                int ci = fe / IHW;
                int rem = fe - ci * IHW;
                int lr = rem / WIN;
                int lc = rem - lr * WIN;
                const float* gsrc = inb + (size_t)(cb0 + ci) * (HIN * WIN)
                                  + (size_t)(gr0 + lr) * WIN + lc;
                gload_lds16(gsrc, bb + i * 256);
            }
        } else if (WIN >= 64) {
            for (int r = wvid; r < CB * IH_T; r += NW) {
                int ci = r / IH_T, lr = r - ci * IH_T;
                int gr = gr0 + lr;
                float* ldst = bb + (ci * IH_T + lr) * WIN;
                if (gr >= 0 && gr < HIN) {
                    const float* gsrc = inb + (size_t)(cb0 + ci) * HIN * WIN + (size_t)gr * WIN;
#pragma unroll
                    for (int s = 0; s < SEGS; ++s)
                        gload_lds4(gsrc + s * 64 + lane, ldst + s * 64);
                } else {
#pragma unroll
                    for (int s = 0; s < SEGS; ++s) ldst[s * 64 + lane] = 0.0f;
                }
            }
        } else {
            for (int pz = wvid; pz < CB * PAIRS; pz += NW) {
                int ci = pz / PAIRS, q = pz - ci * PAIRS;
                int lr0 = q * 2;
                int nr = (lr0 + 1 < IH_T) ? 2 : 1;
                int grr = gr0 + lr0;
                float* ldst = bb + (ci * IH_T + lr0) * WIN;
                if (nr == 2 && grr >= 0 && grr + 1 < HIN) {
                    const float* gsrc = inb + (size_t)(cb0 + ci) * HIN * WIN + (size_t)grr * WIN + lane;
                    gload_lds4(gsrc, ldst);
                } else {
                    for (int e = lane; e < nr * WIN; e += 64) {
                        int rr = e / WIN, cc = e - rr * WIN;
                        int gr = grr + rr;
                        ldst[e] = (gr >= 0 && gr < HIN)
                            ? inb[(size_t)(cb0 + ci) * HIN * WIN + (size_t)gr * WIN + cc] : 0.0f;
                    }
                }
            }
        }
    };

    stage(0, 0);

    if (HSE_IN > 0) {
        if (tid < HSE_IN) {
            float a = se_b1[tid];
            for (int c = 0; c < CIN; ++c)
                a = fmaf(se_sums_in[b * CIN + c] * inv_spatial, se_w1[tid * CIN + c], a);
            hid[tid] = fmaxf(a, 0.0f);
        }
        __syncthreads();
        if (tid < CIN) {
            float a = se_b2[tid];
            for (int h = 0; h < HSE_IN; ++h)
                a = fmaf(hid[h], se_w2[tid * HSE_IN + h], a);
            scl[tid] = 1.0f / (1.0f + expf(-a));
        }
    } else {
        for (int t = tid; t < CIN; t += NTHREADS) scl[t] = 1.0f;
    }
    if (tid < COB) {
        int co = g * COB + tid;
        if (BN_RELU) {
            gl[tid] = gamma[co] * BN_INV_F;
            bl[tid] = beta[co];
        } else {
            gl[tid] = (kk == 0) ? gamma[co] : 0.0f;
        }
    }

    float acc[PPT][COB];
#pragma unroll
    for (int p = 0; p < PPT; ++p)
#pragma unroll
        for (int co = 0; co < COB; ++co) acc[p][co] = 0.0f;

    int cur = 0;
    for (int c = 0; c < NCHUNK; ++c) {
        asm volatile("s_waitcnt vmcnt(0)" ::: "memory");
        __syncthreads();
        if (c + 1 < NCHUNK) stage(c + 1, cur ^ 1);

        const float* bb = &in_t[cur][0];
#pragma unroll
        for (int ci = 0; ci < CB; ++ci) {
            const int cw = cin0 + c * CB + ci;
            const float sc = scl[cw];
            const float* wtap = wt + (size_t)cw * 9 * COUT + g * COB;
            const float* bb_ci = bb + ci * IH_T * WIN;
#pragma unroll
            for (int kh = 0; kh < 3; ++kh) {
#pragma unroll
                for (int kw = 0; kw < 3; ++kw) {
                    const float* wrow = wtap + (kh * 3 + kw) * COUT;
#pragma unroll
                    for (int p = 0; p < PPT; ++p) {
                        const float* row = bb_ci + ((rg + p * ROWS_T) * STRIDE + kh) * WIN;
                        int wi = wos + kw - 1;
                        float v;
                        if (kw == 0) {
                            v = row[wi < 0 ? 0 : wi];
                            if (wi < 0) v = 0.0f;
                        } else if (STRIDE == 1 && kw == 2) {
                            v = row[wi >= WIN ? WIN - 1 : wi];
                            if (wi >= WIN) v = 0.0f;
                        } else {
                            v = row[wi];
                        }
                        v *= sc;
#pragma unroll
                        for (int co = 0; co < COB; ++co)
                            acc[p][co] = fmaf(wrow[co], v, acc[p][co]);
                    }
                }
            }
        }
        cur ^= 1;
    }

    float tsum[COB];
#pragma unroll
    for (int co = 0; co < COB; ++co) tsum[co] = 0.0f;
    float* ob = out + (size_t)kk * pstride
              + ((size_t)b * COUT + (size_t)g * COB) * HOUT * WOUT;
#pragma unroll
    for (int p = 0; p < PPT; ++p) {
        const int ho = ty * TH + rg + p * ROWS_T;
#pragma unroll
        for (int co = 0; co < COB; ++co) {
            float v;
            if (BN_RELU)
                v = fmaxf(fmaf(acc[p][co], gl[co], bl[co]), 0.0f);
            else
                v = acc[p][co] + gl[co];
            ob[(size_t)co * HOUT * WOUT + ho * WOUT + wo] = v;
            tsum[co] += v;
        }
    }

    if (SE_SUM) {
#pragma unroll
        for (int co = 0; co < COB; ++co) {
            float v = tsum[co];
            for (int off = 32; off; off >>= 1) v += __shfl_down(v, off, 64);
            if (lane == 0) red[wvid][co] = v;
        }
        __syncthreads();
        if (tid < COB) {
            float v = 0.0f;
#pragma unroll
            for (int k = 0; k < NW; ++k) v += red[k][tid];
            atomicAdd(&se_sum[b * COUT + g * COB + tid], v);
        }
    }
}

// ---------------------------------------------------------------------------
// Wave-split conv body (conv2 / conv3), STRIDE==2, de-interleaved LDS rows,
// TWO-DEEP counted-vmcnt pipeline (3 buffers, raw s_barrier, vmcnt(NPW)).
// Interior blocks: uniform NPW DMAs/wave/stage. Boundary blocks: full drain.
// ---------------------------------------------------------------------------
template <int CIN, int CINB, int COUT, int WCO, int HIN, int HOUT, int STRIDE,
          int TW, int PPT, int CB, int NTHREADS,
          bool BN_RELU, bool SE_SUM, int HSE_IN, int KSPLIT>
__device__ __forceinline__ void conv_ws_body(
    const float* __restrict__ in, const float* __restrict__ wt,
    const float* __restrict__ gamma, const float* __restrict__ beta,
    float* __restrict__ out, size_t pstride,
    float* __restrict__ se_sum, const float* __restrict__ se_sums_in,
    const float* __restrict__ se_w1, const float* __restrict__ se_b1,
    const float* __restrict__ se_w2, const float* __restrict__ se_b2,
    float inv_spatial)
{
    constexpr int WIN = HIN, WOUT = HOUT;
    constexpr int NW = NTHREADS / 64;
    constexpr int WROWS = 64 / TW;
    constexpr int TH = WROWS * PPT;
    constexpr int IH_T = (TH - 1) * STRIDE + 3;
    constexpr int COBT = NW * WCO;
    constexpr int NG = COUT / COBT;
    constexpr int NCHUNK = CINB / CB;
    constexpr int SEGS = WIN / 64;
    constexpr int HALF = WIN / 2;
    constexpr int ROWS = CB * IH_T;
    constexpr int NPW = (ROWS / NW) * SEGS;   // DMAs per wave per stage (interior)
    static_assert(STRIDE == 2, "wave-split body is stride-2 only");
    static_assert(TW == WOUT, "tile spans full width");
    static_assert(CINB % CB == 0, "chunking");
    static_assert(WIN % 64 == 0, "stage width");
    static_assert(COUT % COBT == 0, "cout split");
    static_assert(ROWS % NW == 0, "uniform DMA count per wave");
    static_assert(NCHUNK >= 2, "pipeline depth");

    const int b = blockIdx.z;
    const int gy = blockIdx.y;
    const int ty = blockIdx.x;
    const int tid = threadIdx.x;
    const int lane = tid & 63;
    const int wvu = __builtin_amdgcn_readfirstlane(tid >> 6);
    const int wo = lane % TW;
    const int rl = lane / TW;
    const int g = gy % NG;
    const int kk = gy / NG;
    const int cin0 = kk * CINB;

    __shared__ float in_t[3][CB * IH_T * WIN];
    __shared__ float scl[CIN];
    __shared__ float gl[COBT], bl[COBT];
    __shared__ float red[NW][WCO];
    __shared__ float hid[HSE_IN > 0 ? HSE_IN : 1];

    const float* inb = in + (size_t)b * CIN * HIN * WIN;
    const int gr0 = ty * TH * STRIDE - 1;
    const bool interior = (gr0 >= 0) && (gr0 + IH_T <= HIN);

    // de-interleaved staging: LDS row = [E(HALF) | O(HALF)]; 4B DMA, per-lane src
    auto stage = [&](int c, int buf) {
        const int cb0 = cin0 + c * CB;
        float* bb = &in_t[buf][0];
        if (interior) {
            for (int r = wvu; r < ROWS; r += NW) {
                int ci = r / IH_T, lr = r - ci * IH_T;
                const float* gsrc = inb + (size_t)(cb0 + ci) * HIN * WIN + (size_t)(gr0 + lr) * WIN;
                float* ldst = bb + r * WIN;
#pragma unroll
                for (int s = 0; s < SEGS; ++s) {
                    int p = s * 64 + lane;
                    int half = p / HALF;
                    int idx = p - half * HALF;
                    gload_lds4(gsrc + 2 * idx + half, ldst + s * 64);
                }
            }
        } else {
            for (int r = wvu; r < ROWS; r += NW) {
                int ci = r / IH_T, lr = r - ci * IH_T;
                int gr = gr0 + lr;
                float* ldst = bb + r * WIN;
                if (gr >= 0 && gr < HIN) {
                    const float* gsrc = inb + (size_t)(cb0 + ci) * HIN * WIN + (size_t)gr * WIN;
#pragma unroll
                    for (int s = 0; s < SEGS; ++s) {
                        int p = s * 64 + lane;
                        int half = p / HALF;
                        int idx = p - half * HALF;
                        gload_lds4(gsrc + 2 * idx + half, ldst + s * 64);
                    }
                } else {
#pragma unroll
                    for (int s = 0; s < SEGS; ++s) ldst[s * 64 + lane] = 0.0f;
                }
            }
        }
    };

    // ---- SE scale / BN params (standard barriers; before any DMA) ----
    if (HSE_IN > 0) {
        if (tid < HSE_IN) {
            float a = se_b1[tid];
            for (int c = 0; c < CIN; ++c)
                a = fmaf(se_sums_in[b * CIN + c] * inv_spatial, se_w1[tid * CIN + c], a);
            hid[tid] = fmaxf(a, 0.0f);
        }
        __syncthreads();
        if (tid < CIN) {
            float a = se_b2[tid];
            for (int h = 0; h < HSE_IN; ++h)
                a = fmaf(hid[h], se_w2[tid * HSE_IN + h], a);
            scl[tid] = 1.0f / (1.0f + expf(-a));
        }
    } else {
        for (int t = tid; t < CIN; t += NTHREADS) scl[t] = 1.0f;
    }
    if (tid < COBT) {
        int co = g * COBT + tid;
        if (BN_RELU) {
            gl[tid] = gamma[co] * BN_INV_F;
            bl[tid] = beta[co];
        } else {
            gl[tid] = (kk == 0) ? gamma[co] : 0.0f;
        }
    }
    __syncthreads();   // scl/gl visible to all waves

    // ---- two-deep prologue ----
    stage(0, 0);
    stage(1, 1);

    float acc[PPT][WCO];
#pragma unroll
    for (int p = 0; p < PPT; ++p)
#pragma unroll
        for (int co = 0; co < WCO; ++co) acc[p][co] = 0.0f;

    for (int c = 0; c < NCHUNK; ++c) {
        if (interior) {
            if (c + 1 < NCHUNK)
                asm volatile("s_waitcnt vmcnt(%0)" :: "i"(NPW) : "memory");
            else
                asm volatile("s_waitcnt vmcnt(0)" ::: "memory");
        } else {
            asm volatile("s_waitcnt vmcnt(0) lgkmcnt(0)" ::: "memory");
        }
        __builtin_amdgcn_s_barrier();
        __builtin_amdgcn_sched_barrier(0);
        if (c + 2 < NCHUNK) stage(c + 2, (c + 2) % 3);

        const float* bb = &in_t[c % 3][0];
#pragma unroll
        for (int ci = 0; ci < CB; ++ci) {
            const int cw = cin0 + c * CB + ci;
            const float sc = scl[cw];
            const float* wtap = wt + (size_t)cw * 9 * COUT + g * COBT + wvu * WCO;
            const float* bb_ci = bb + ci * IH_T * WIN;
#pragma unroll
            for (int kh = 0; kh < 3; ++kh) {
                float iwv[PPT][3];
#pragma unroll
                for (int p = 0; p < PPT; ++p) {
                    const float* row = bb_ci + ((rl + p * WROWS) * STRIDE + kh) * WIN;
                    float e  = row[wo];
                    float om = row[HALF + ((wo == 0) ? 0 : wo - 1)];
                    if (wo == 0) om = 0.0f;
                    float op = row[HALF + wo];
                    iwv[p][0] = om * sc;
                    iwv[p][1] = e * sc;
                    iwv[p][2] = op * sc;
                }
#pragma unroll
                for (int kw = 0; kw < 3; ++kw) {
                    const float* wrow = wtap + (kh * 3 + kw) * COUT;  // uniform -> SGPR
#pragma unroll
                    for (int p = 0; p < PPT; ++p) {
                        const float v = iwv[p][kw];
#pragma unroll
                        for (int co = 0; co < WCO; ++co)
                            acc[p][co] = fmaf(wrow[co], v, acc[p][co]);
                    }
                }
            }
        }
    }

    float tsum[WCO];
#pragma unroll
    for (int co = 0; co < WCO; ++co) tsum[co] = 0.0f;
    float* ob = out + (size_t)kk * pstride
              + ((size_t)b * COUT + (size_t)g * COBT + (size_t)wvu * WCO) * HOUT * WOUT;
#pragma unroll
    for (int p = 0; p < PPT; ++p) {
        const int ho = ty * TH + rl + p * WROWS;
#pragma unroll
        for (int co = 0; co < WCO; ++co) {
            float v;
            if (BN_RELU)
                v = fmaxf(fmaf(acc[p][co], gl[wvu * WCO + co], bl[wvu * WCO + co]), 0.0f);
            else
                v = acc[p][co] + gl[wvu * WCO + co];
            ob[(size_t)co * HOUT * WOUT + ho * WOUT + wo] = v;
            tsum[co] += v;
        }
    }

    if (SE_SUM) {
#pragma unroll
        for (int co = 0; co < WCO; ++co) {
            float v = tsum[co];
            for (int off = 32; off; off >>= 1) v += __shfl_down(v, off, 64);
            if (lane == 0) red[wvu][co] = v;
        }
        __syncthreads();
        if (lane < WCO)
            atomicAdd(&se_sum[b * COUT + g * COBT + wvu * WCO + lane], red[wvu][lane]);
    }
}

#define CONV_ARGS \
    const float* __restrict__ in, const float* __restrict__ wt, \
    const float* __restrict__ gamma, const float* __restrict__ beta, \
    float* __restrict__ out, size_t pstride, float* __restrict__ se_sum, \
    const float* __restrict__ se_sums_in, \
    const float* __restrict__ se_w1, const float* __restrict__ se_b1, \
    const float* __restrict__ se_w2, const float* __restrict__ se_b2, \
    float inv_spatial
#define CONV_PASS in, wt, gamma, beta, out, pstride, se_sum, se_sums_in, \
    se_w1, se_b1, se_w2, se_b2, inv_spatial

__global__ __launch_bounds__(256) void conv1_k(CONV_ARGS) {
    conv_body<1, 1, 16, 16, 128, 128, 1, 128, 2, 2, 1, 256, true, true, 0, 1>(CONV_PASS);
}
// conv2: 4 waves x 8 couts, PPT=2 (TH=2, IH_T=5), CB=4, NPW=10. 2048 blocks.
__global__ __launch_bounds__(256) void conv2_k(CONV_ARGS) {
    conv_ws_body<16, 16, 32, 8, 128, 64, 2, 64, 2, 4, 256, true, true, 1, 1>(CONV_PASS);
}
// conv3: 4 waves x 16 couts, PPT=1 (TH=2, IH_T=5), CB=8, NPW=10. 1024 blocks.
__global__ __launch_bounds__(256) void conv3_k(CONV_ARGS) {
    conv_ws_body<32, 32, 64, 16, 64, 32, 2, 32, 1, 8, 256, true, true, 2, 1>(CONV_PASS);
}
__global__ __launch_bounds__(256) void pc_k(CONV_ARGS) {
    conv_body<64, 16, 64, 16, 32, 16, 2, 16, 16, 1, 4, 256, false, false, 4, 4>(CONV_PASS);
}

// ---------------------------------------------------------------------------
// Fused squash + u_hat. Block = 256 capsules.
// ---------------------------------------------------------------------------
__global__ __launch_bounds__(256) void squash_uhat_k(
    const float* __restrict__ up, size_t pstride,
    const float* __restrict__ W, float* __restrict__ u_hat)
{
    const int base = blockIdx.x * 256;
    const int tid = threadIdx.x;
    __shared__ float ush[256][8];

    {
        const int cap = base + tid;
        const int b = cap >> 11, i = cap & 2047;
        const int chi = i >> 8, spx = i & 255;
        const size_t off = ((size_t)(b * 64 + chi * 8)) * 256 + spx;
        float s[8];
        float n2 = 0.0f;
#pragma unroll
        for (int j = 0; j < 8; j++) {
            const size_t o = off + (size_t)j * 256;
            s[j] = (up[o] + up[o + pstride]) + (up[o + 2 * pstride] + up[o + 3 * pstride]);
            n2 = fmaf(s[j], s[j], n2);
        }
        const float n = sqrtf(n2);
        const float f = (n2 / (1.0f + n2)) / (n + 1e-8f);
#pragma unroll
        for (int j = 0; j < 8; j++) ush[tid][j] = s[j] * f;
    }
    __syncthreads();

    float* ob = u_hat + (size_t)base * 48;
#pragma unroll 4
    for (int k = 0; k < 48; ++k) {
        int o = tid + k * 256;
        int c = o / 48, cd = o % 48;
        int gi = (base + c) & 2047;
        const float* wp = W + (size_t)gi * 384 + cd * 8;
        float a = 0.0f;
#pragma unroll
        for (int e = 0; e < 8; e++) a = fmaf(wp[e], ush[c][e], a);
        ob[o] = a;
    }
}

// ---------------------------------------------------------------------------
template <int IT>
__global__ __launch_bounds__(256) void sweep_k(const float* __restrict__ u_hat,
                                               const float* __restrict__ s_hist,
                                               float* __restrict__ s_out)
{
    const int b = blockIdx.y;
    const int i = blockIdx.x * 256 + threadIdx.x;
    const int tid = threadIdx.x;
    __shared__ float vsh[IT > 0 ? IT : 1][48];
    __shared__ float fac[IT > 0 ? IT : 1][3];
    __shared__ float red[4][48];

    const float4* qp = (const float4*)(u_hat + ((size_t)b * 2048 + i) * 48);
    float uhv[48];
#pragma unroll
    for (int q = 0; q < 12; ++q) {
        float4 t = qp[q];
        uhv[q * 4 + 0] = t.x; uhv[q * 4 + 1] = t.y;
        uhv[q * 4 + 2] = t.z; uhv[q * 4 + 3] = t.w;
    }

    if (IT > 0) {
        if (tid < IT * 48) {
            int t = tid / 48, c = tid % 48;
            vsh[t][c] = s_hist[((size_t)t * 64 + b) * 48 + c];
        }
        __syncthreads();
        if (tid < IT * 3) {
            int t = tid / 3, j = tid % 3;
            float n2 = 0.0f;
            for (int d = 0; d < 16; ++d) { float s = vsh[t][j * 16 + d]; n2 = fmaf(s, s, n2); }
            float n = sqrtf(n2);
            fac[t][j] = (n2 / (1.0f + n2)) / (n + 1e-8f);
        }
        __syncthreads();
        if (tid < IT * 48) {
            int t = tid / 48, c = tid % 48;
            vsh[t][c] *= fac[t][c / 16];
        }
        __syncthreads();
    }

    float c0, c1, c2;
    if (IT == 0) {
        c0 = c1 = c2 = (1.0f / 3.0f);
    } else {
        float b0 = 0.0f, b1 = 0.0f, b2 = 0.0f;
#pragma unroll
        for (int t = 0; t < IT; ++t)
#pragma unroll
            for (int d = 0; d < 16; ++d) {
                b0 = fmaf(uhv[d],      vsh[t][d],      b0);
                b1 = fmaf(uhv[16 + d], vsh[t][16 + d], b1);
                b2 = fmaf(uhv[32 + d], vsh[t][32 + d], b2);
            }
        float m = fmaxf(b0, fmaxf(b1, b2));
        float e0 = expf(b0 - m), e1 = expf(b1 - m), e2 = expf(b2 - m);
        float inv = 1.0f / (e0 + e1 + e2);
        c0 = e0 * inv; c1 = e1 * inv; c2 = e2 * inv;
    }

    float sp[48];
#pragma unroll
    for (int d = 0; d < 16; ++d) {
        sp[d]      = c0 * uhv[d];
        sp[16 + d] = c1 * uhv[16 + d];
        sp[32 + d] = c2 * uhv[32 + d];
    }
    const int lane = tid & 63, wv = tid >> 6;
#pragma unroll
    for (int j = 0; j < 48; ++j) {
        float x = sp[j];
        for (int off = 32; off; off >>= 1) x += __shfl_down(x, off, 64);
        if (lane == 0) red[wv][j] = x;
    }
    __syncthreads();
    if (tid < 48) {
        float x = red[0][tid] + red[1][tid] + red[2][tid] + red[3][tid];
        atomicAdd(&s_out[(size_t)b * 48 + tid], x);
    }
}

// ---------------------------------------------------------------------------
__global__ __launch_bounds__(64) void route_out_k(const float* __restrict__ s2,
                                                  float* __restrict__ out)
{
    const int b = blockIdx.x;
    __shared__ float s[48];
    if (threadIdx.x < 48) s[threadIdx.x] = s2[(size_t)b * 48 + threadIdx.x];
    __syncthreads();
    if (threadIdx.x < 3) {
        int j = threadIdx.x;
        float n2 = 0.0f;
        for (int d = 0; d < 16; ++d) { float v = s[j * 16 + d]; n2 = fmaf(v, v, n2); }
        float n = sqrtf(n2);
        float fc = (n2 / (1.0f + n2)) / (n + 1e-8f);
        out[b * 3 + j] = fc * n;
    }
}

// ---------------------------------------------------------------------------
extern "C" void kernel_launch(void* const* d_in, const int* in_sizes, int n_in,
                              void* d_out, int out_size, void* d_ws, size_t ws_size,
                              hipStream_t stream)
{
    const float* x       = (const float*)d_in[0];
    const float* conv1_w = (const float*)d_in[1];
    const float* bn1_g   = (const float*)d_in[2];
    const float* bn1_b   = (const float*)d_in[3];
    const float* se1_w1  = (const float*)d_in[4];
    const float* se1_b1  = (const float*)d_in[5];
    const float* se1_w2  = (const float*)d_in[6];
    const float* se1_b2  = (const float*)d_in[7];
    const float* conv2_w = (const float*)d_in[8];
    const float* bn2_g   = (const float*)d_in[9];
    const float* bn2_b   = (const float*)d_in[10];
    const float* se2_w1  = (const float*)d_in[11];
    const float* se2_b1  = (const float*)d_in[12];
    const float* se2_w2  = (const float*)d_in[13];
    const float* se2_b2  = (const float*)d_in[14];
    const float* conv3_w = (const float*)d_in[15];
    const float* bn3_g   = (const float*)d_in[16];
    const float* bn3_b   = (const float*)d_in[17];
    const float* se3_w1  = (const float*)d_in[18];
    const float* se3_b1  = (const float*)d_in[19];
    const float* se3_w2  = (const float*)d_in[20];
    const float* se3_b2  = (const float*)d_in[21];
    const float* pc_w    = (const float*)d_in[22];
    const float* pc_b    = (const float*)d_in[23];
    const float* W_digit = (const float*)d_in[24];  // (1,2048,3,16,8)

    float* ws = (float*)d_ws;
    float* h1     = ws;
    float* h2     = ws + 16777216;
    float* h3     = ws;                  // overlays dead h1 (conv3 writes here)
    float* uparts = ws + 4194304;
    float* u_hat  = ws + 9437184;
    float* sums   = ws + 25165824;
    float* s1 = sums, *s2 = sums + 1024, *s3 = sums + 3072;
    float* s_buf  = sums + 7168;
    float* w1t    = ws + 25182272;
    float* w2t    = w1t + 144;
    float* w3t    = w2t + 4608;
    float* wpt    = w3t + 18432;

    hipMemsetAsync(sums, 0, 16448 * sizeof(float), stream);
    wtrans_all_k<<<235, 256, 0, stream>>>(conv1_w, conv2_w, conv3_w, pc_w,
                                          w1t, w2t, w3t, wpt);

    // conv1: 1->16, 128x128, s1. 2048 blocks.
    conv1_k<<<dim3(32, 1, 64), 256, 0, stream>>>(
        x, w1t, bn1_g, bn1_b, h1, 0, s1,
        nullptr, nullptr, nullptr, nullptr, nullptr, 0.0f);

    // conv2: 16->32, ->64x64, s2. Wave-split 4x8, PPT=2, counted pipeline. 2048 blocks.
    conv2_k<<<dim3(32, 1, 64), 256, 0, stream>>>(
        h1, w2t, bn2_g, bn2_b, h2, 0, s2,
        s1, se1_w1, se1_b1, se1_w2, se1_b2, 1.0f / 16384.0f);

    // conv3: 32->64, ->32x32, s2. Wave-split 4x16, PPT=1, counted pipeline. 1024 blocks.
    conv3_k<<<dim3(16, 1, 64), 256, 0, stream>>>(
        h2, w3t, bn3_g, bn3_b, h3, 0, s3,
        s2, se2_w1, se2_b1, se2_w2, se2_b2, 1.0f / 4096.0f);

    // primary caps: 64->64, ->16x16, s2, +bias. COB=16/NG=4, KSPLIT=4, CB=4.
    pc_k<<<dim3(1, 16, 64), 256, 0, stream>>>(
        h3, wpt, pc_b, nullptr, uparts, (size_t)1048576, nullptr,
        s3, se3_w1, se3_b1, se3_w2, se3_b2, 1.0f / 1024.0f);

    squash_uhat_k<<<512, 256, 0, stream>>>(uparts, (size_t)1048576, W_digit, u_hat);

    sweep_k<0><<<dim3(8, 64), 256, 0, stream>>>(u_hat, s_buf, s_buf + 0 * 64 * 48);
    sweep_k<1><<<dim3(8, 64), 256, 0, stream>>>(u_hat, s_buf, s_buf + 1 * 64 * 48);
    sweep_k<2><<<dim3(8, 64), 256, 0, stream>>>(u_hat, s_buf, s_buf + 2 * 64 * 48);
    route_out_k<<<64, 64, 0, stream>>>(s_buf + 2 * 64 * 48, (float*)d_out);
}

// Round 17
// 212.530 us; speedup vs baseline: 1.0717x; 1.0566x over previous
//
#include <hip/hip_runtime.h>
#include <math.h>

#define BN_INV_F 0.9999950000374997f

__device__ __forceinline__ void gload_lds4(const float* g, float* l) {
    __builtin_amdgcn_global_load_lds(
        (const __attribute__((address_space(1))) void*)g,
        (__attribute__((address_space(3))) void*)l, 4, 0, 0);
}
__device__ __forceinline__ void gload_lds16(const float* g, float* l) {
    __builtin_amdgcn_global_load_lds(
        (const __attribute__((address_space(1))) void*)g,
        (__attribute__((address_space(3))) void*)l, 16, 0, 0);
}

// ---------------------------------------------------------------------------
// Weight transpose (once): wt[(cin*9+k)*COUT + co] = w[co][cin][k]
// ---------------------------------------------------------------------------
__global__ __launch_bounds__(256) void wtrans_all_k(
    const float* __restrict__ w1, const float* __restrict__ w2,
    const float* __restrict__ w3, const float* __restrict__ wp,
    float* __restrict__ w1t, float* __restrict__ w2t,
    float* __restrict__ w3t, float* __restrict__ wpt)
{
    int i = blockIdx.x * 256 + threadIdx.x;
    if (i < 144) {
        int co = i % 16, k = i / 16;
        w1t[i] = w1[co * 9 + k];
    } else if (i < 4752) {
        int t = i - 144;
        int co = t % 32, rk = t / 32, cin = rk / 9, k = rk % 9;
        w2t[t] = w2[(co * 16 + cin) * 9 + k];
    } else if (i < 23184) {
        int t = i - 4752;
        int co = t % 64, rk = t / 64, cin = rk / 9, k = rk % 9;
        w3t[t] = w3[(co * 32 + cin) * 9 + k];
    } else if (i < 60048) {
        int t = i - 23184;
        int co = t % 64, rk = t / 64, cin = rk / 9, k = rk % 9;
        wpt[t] = wp[(co * 64 + cin) * 9 + k];
    }
}

// ---------------------------------------------------------------------------
// Original conv body (conv1 / pc): thread-split couts, 2-buffer drain scheme.
// ---------------------------------------------------------------------------
template <int CIN, int CINB, int COUT, int COB, int HIN, int HOUT, int STRIDE,
          int TW, int ROWS_T, int PPT, int CB, int NTHREADS,
          bool BN_RELU, bool SE_SUM, int HSE_IN, int KSPLIT>
__device__ __forceinline__ void conv_body(
    const float* __restrict__ in, const float* __restrict__ wt,
    const float* __restrict__ gamma, const float* __restrict__ beta,
    float* __restrict__ out, size_t pstride,
    float* __restrict__ se_sum, const float* __restrict__ se_sums_in,
    const float* __restrict__ se_w1, const float* __restrict__ se_b1,
    const float* __restrict__ se_w2, const float* __restrict__ se_b2,
    float inv_spatial)
{
    constexpr int WIN = HIN, WOUT = HOUT;
    constexpr int TH = ROWS_T * PPT;
    constexpr int IH_T = (TH - 1) * STRIDE + 3;
    constexpr int NW = NTHREADS / 64;
    constexpr int NCHUNK = CINB / CB;
    constexpr int SEGS = (WIN >= 64) ? (WIN / 64) : 1;
    constexpr int PAIRS = (IH_T + 1) / 2;
    constexpr int NG = COUT / COB;
    constexpr int IHW = IH_T * WIN;
    constexpr int CHUNK_BYTES = CB * IHW * 4;
    constexpr bool FAST16 = (CHUNK_BYTES % 1024) == 0;
    constexpr int NISS = CHUNK_BYTES / 1024;
    static_assert(NTHREADS == TW * ROWS_T, "geometry");
    static_assert(TW == WOUT, "tile must span full output width");
    static_assert(CINB % CB == 0, "chunking");
    static_assert(WIN % 64 == 0 || WIN == 32, "stage width");

    const int b = blockIdx.z;
    const int gy = blockIdx.y;
    const int ty = blockIdx.x;
    const int tid = threadIdx.x;
    const int wo = tid % TW;
    const int rg = tid / TW;
    const int g = gy % NG;
    const int kk = gy / NG;
    const int cin0 = kk * CINB;

    __shared__ float in_t[2][CB * IH_T * WIN];
    __shared__ float scl[CIN];
    __shared__ float gl[COB], bl[COB];
    __shared__ float red[NW][COB];
    __shared__ float hid[HSE_IN > 0 ? HSE_IN : 1];

    const float* inb = in + (size_t)b * CIN * HIN * WIN;
    const int gr0 = ty * TH * STRIDE - 1;
    const int wos = wo * STRIDE;
    const int wvid = tid >> 6, lane = tid & 63;
    const bool interior = (gr0 >= 0) && (gr0 + IH_T <= HIN);

    auto stage = [&](int c, int buf) {
        const int cb0 = cin0 + c * CB;
        float* bb = &in_t[buf][0];
        if (FAST16 && interior) {
            for (int i = wvid; i < NISS; i += NW) {
                int fe = i * 256 + lane * 4;
                int ci = fe / IHW;
                int rem = fe - ci * IHW;
                int lr = rem / WIN;
                int lc = rem - lr * WIN;
                const float* gsrc = inb + (size_t)(cb0 + ci) * (HIN * WIN)
                                  + (size_t)(gr0 + lr) * WIN + lc;
                gload_lds16(gsrc, bb + i * 256);
            }
        } else if (WIN >= 64) {
            for (int r = wvid; r < CB * IH_T; r += NW) {
                int ci = r / IH_T, lr = r - ci * IH_T;
                int gr = gr0 + lr;
                float* ldst = bb + (ci * IH_T + lr) * WIN;
                if (gr >= 0 && gr < HIN) {
                    const float* gsrc = inb + (size_t)(cb0 + ci) * HIN * WIN + (size_t)gr * WIN;
#pragma unroll
                    for (int s = 0; s < SEGS; ++s)
                        gload_lds4(gsrc + s * 64 + lane, ldst + s * 64);
                } else {
#pragma unroll
                    for (int s = 0; s < SEGS; ++s) ldst[s * 64 + lane] = 0.0f;
                }
            }
        } else {
            for (int pz = wvid; pz < CB * PAIRS; pz += NW) {
                int ci = pz / PAIRS, q = pz - ci * PAIRS;
                int lr0 = q * 2;
                int nr = (lr0 + 1 < IH_T) ? 2 : 1;
                int grr = gr0 + lr0;
                float* ldst = bb + (ci * IH_T + lr0) * WIN;
                if (nr == 2 && grr >= 0 && grr + 1 < HIN) {
                    const float* gsrc = inb + (size_t)(cb0 + ci) * HIN * WIN + (size_t)grr * WIN + lane;
                    gload_lds4(gsrc, ldst);
                } else {
                    for (int e = lane; e < nr * WIN; e += 64) {
                        int rr = e / WIN, cc = e - rr * WIN;
                        int gr = grr + rr;
                        ldst[e] = (gr >= 0 && gr < HIN)
                            ? inb[(size_t)(cb0 + ci) * HIN * WIN + (size_t)gr * WIN + cc] : 0.0f;
                    }
                }
            }
        }
    };

    stage(0, 0);

    if (HSE_IN > 0) {
        if (tid < HSE_IN) {
            float a = se_b1[tid];
            for (int c = 0; c < CIN; ++c)
                a = fmaf(se_sums_in[b * CIN + c] * inv_spatial, se_w1[tid * CIN + c], a);
            hid[tid] = fmaxf(a, 0.0f);
        }
        __syncthreads();
        if (tid < CIN) {
            float a = se_b2[tid];
            for (int h = 0; h < HSE_IN; ++h)
                a = fmaf(hid[h], se_w2[tid * HSE_IN + h], a);
            scl[tid] = 1.0f / (1.0f + expf(-a));
        }
    } else {
        for (int t = tid; t < CIN; t += NTHREADS) scl[t] = 1.0f;
    }
    if (tid < COB) {
        int co = g * COB + tid;
        if (BN_RELU) {
            gl[tid] = gamma[co] * BN_INV_F;
            bl[tid] = beta[co];
        } else {
            gl[tid] = (kk == 0) ? gamma[co] : 0.0f;
        }
    }

    float acc[PPT][COB];
#pragma unroll
    for (int p = 0; p < PPT; ++p)
#pragma unroll
        for (int co = 0; co < COB; ++co) acc[p][co] = 0.0f;

    int cur = 0;
    for (int c = 0; c < NCHUNK; ++c) {
        asm volatile("s_waitcnt vmcnt(0)" ::: "memory");
        __syncthreads();
        if (c + 1 < NCHUNK) stage(c + 1, cur ^ 1);

        const float* bb = &in_t[cur][0];
#pragma unroll
        for (int ci = 0; ci < CB; ++ci) {
            const int cw = cin0 + c * CB + ci;
            const float sc = scl[cw];
            const float* wtap = wt + (size_t)cw * 9 * COUT + g * COB;
            const float* bb_ci = bb + ci * IH_T * WIN;
#pragma unroll
            for (int kh = 0; kh < 3; ++kh) {
#pragma unroll
                for (int kw = 0; kw < 3; ++kw) {
                    const float* wrow = wtap + (kh * 3 + kw) * COUT;
#pragma unroll
                    for (int p = 0; p < PPT; ++p) {
                        const float* row = bb_ci + ((rg + p * ROWS_T) * STRIDE + kh) * WIN;
                        int wi = wos + kw - 1;
                        float v;
                        if (kw == 0) {
                            v = row[wi < 0 ? 0 : wi];
                            if (wi < 0) v = 0.0f;
                        } else if (STRIDE == 1 && kw == 2) {
                            v = row[wi >= WIN ? WIN - 1 : wi];
                            if (wi >= WIN) v = 0.0f;
                        } else {
                            v = row[wi];
                        }
                        v *= sc;
#pragma unroll
                        for (int co = 0; co < COB; ++co)
                            acc[p][co] = fmaf(wrow[co], v, acc[p][co]);
                    }
                }
            }
        }
        cur ^= 1;
    }

    float tsum[COB];
#pragma unroll
    for (int co = 0; co < COB; ++co) tsum[co] = 0.0f;
    float* ob = out + (size_t)kk * pstride
              + ((size_t)b * COUT + (size_t)g * COB) * HOUT * WOUT;
#pragma unroll
    for (int p = 0; p < PPT; ++p) {
        const int ho = ty * TH + rg + p * ROWS_T;
#pragma unroll
        for (int co = 0; co < COB; ++co) {
            float v;
            if (BN_RELU)
                v = fmaxf(fmaf(acc[p][co], gl[co], bl[co]), 0.0f);
            else
                v = acc[p][co] + gl[co];
            ob[(size_t)co * HOUT * WOUT + ho * WOUT + wo] = v;
            tsum[co] += v;
        }
    }

    if (SE_SUM) {
#pragma unroll
        for (int co = 0; co < COB; ++co) {
            float v = tsum[co];
            for (int off = 32; off; off >>= 1) v += __shfl_down(v, off, 64);
            if (lane == 0) red[wvid][co] = v;
        }
        __syncthreads();
        if (tid < COB) {
            float v = 0.0f;
#pragma unroll
            for (int k = 0; k < NW; ++k) v += red[k][tid];
            atomicAdd(&se_sum[b * COUT + g * COB + tid], v);
        }
    }
}

// ---------------------------------------------------------------------------
// Wave-split 2-col conv body (conv2 / conv3), STRIDE==2, de-interleaved LDS
// rows [E|O]. Thread owns a COLUMN PAIR (2*wo2, 2*wo2+1) of one row: per
// (cin,kh) it reads E[2w..2w+1] (b64) + O[2w..2w+1] (b64) + O[2w-1] (b32)
// = 3 LDS instrs (was 6 b32) for the same FMA count. float2 output stores.
// Two-deep counted-vmcnt pipeline (3 buffers).
// ---------------------------------------------------------------------------
template <int CIN, int CINB, int COUT, int WCO, int HIN, int HOUT,
          int TW, int CB, int NTHREADS,
          bool BN_RELU, bool SE_SUM, int HSE_IN>
__device__ __forceinline__ void conv_ws2_body(
    const float* __restrict__ in, const float* __restrict__ wt,
    const float* __restrict__ gamma, const float* __restrict__ beta,
    float* __restrict__ out,
    float* __restrict__ se_sum, const float* __restrict__ se_sums_in,
    const float* __restrict__ se_w1, const float* __restrict__ se_b1,
    const float* __restrict__ se_w2, const float* __restrict__ se_b2,
    float inv_spatial)
{
    constexpr int WIN = HIN, WOUT = HOUT;
    constexpr int STRIDE = 2;
    constexpr int NW = NTHREADS / 64;
    constexpr int NP = TW / 2;                // col-pairs per row
    constexpr int TH = 64 / NP;               // rows per wave
    constexpr int IH_T = (TH - 1) * STRIDE + 3;
    constexpr int COBT = NW * WCO;
    constexpr int NG = COUT / COBT;
    constexpr int NCHUNK = CINB / CB;
    constexpr int SEGS = WIN / 64;
    constexpr int HALF = WIN / 2;
    constexpr int ROWS = CB * IH_T;
    constexpr int NPW = (ROWS / NW) * SEGS;   // DMAs per wave per stage (interior)
    static_assert(TW == WOUT, "tile spans full width");
    static_assert(CINB % CB == 0, "chunking");
    static_assert(WIN % 64 == 0, "stage width");
    static_assert(COUT % COBT == 0, "cout split");
    static_assert(ROWS % NW == 0, "uniform DMA count per wave");
    static_assert(NCHUNK >= 2, "pipeline depth");

    const int b = blockIdx.z;
    const int gy = blockIdx.y;
    const int ty = blockIdx.x;
    const int tid = threadIdx.x;
    const int lane = tid & 63;
    const int wvu = __builtin_amdgcn_readfirstlane(tid >> 6);
    const int wo2 = lane % NP;                // col pair index
    const int rl = lane / NP;                 // row within tile
    const int g = gy % NG;
    const int kk = gy / NG;
    const int cin0 = kk * CINB;

    __shared__ float in_t[3][CB * IH_T * WIN];
    __shared__ float scl[CIN];
    __shared__ float gl[COBT], bl[COBT];
    __shared__ float red[NW][WCO];
    __shared__ float hid[HSE_IN > 0 ? HSE_IN : 1];

    const float* inb = in + (size_t)b * CIN * HIN * WIN;
    const int gr0 = ty * TH * STRIDE - 1;
    const bool interior = (gr0 >= 0) && (gr0 + IH_T <= HIN);

    // de-interleaved staging: LDS row = [E(HALF) | O(HALF)]; 4B DMA, per-lane src
    auto stage = [&](int c, int buf) {
        const int cb0 = cin0 + c * CB;
        float* bb = &in_t[buf][0];
        if (interior) {
            for (int r = wvu; r < ROWS; r += NW) {
                int ci = r / IH_T, lr = r - ci * IH_T;
                const float* gsrc = inb + (size_t)(cb0 + ci) * HIN * WIN + (size_t)(gr0 + lr) * WIN;
                float* ldst = bb + r * WIN;
#pragma unroll
                for (int s = 0; s < SEGS; ++s) {
                    int p = s * 64 + lane;
                    int half = p / HALF;
                    int idx = p - half * HALF;
                    gload_lds4(gsrc + 2 * idx + half, ldst + s * 64);
                }
            }
        } else {
            for (int r = wvu; r < ROWS; r += NW) {
                int ci = r / IH_T, lr = r - ci * IH_T;
                int gr = gr0 + lr;
                float* ldst = bb + r * WIN;
                if (gr >= 0 && gr < HIN) {
                    const float* gsrc = inb + (size_t)(cb0 + ci) * HIN * WIN + (size_t)gr * WIN;
#pragma unroll
                    for (int s = 0; s < SEGS; ++s) {
                        int p = s * 64 + lane;
                        int half = p / HALF;
                        int idx = p - half * HALF;
                        gload_lds4(gsrc + 2 * idx + half, ldst + s * 64);
                    }
                } else {
#pragma unroll
                    for (int s = 0; s < SEGS; ++s) ldst[s * 64 + lane] = 0.0f;
                }
            }
        }
    };

    // ---- SE scale / BN params (before any DMA) ----
    if (HSE_IN > 0) {
        if (tid < HSE_IN) {
            float a = se_b1[tid];
            for (int c = 0; c < CIN; ++c)
                a = fmaf(se_sums_in[b * CIN + c] * inv_spatial, se_w1[tid * CIN + c], a);
            hid[tid] = fmaxf(a, 0.0f);
        }
        __syncthreads();
        if (tid < CIN) {
            float a = se_b2[tid];
            for (int h = 0; h < HSE_IN; ++h)
                a = fmaf(hid[h], se_w2[tid * HSE_IN + h], a);
            scl[tid] = 1.0f / (1.0f + expf(-a));
        }
    } else {
        for (int t = tid; t < CIN; t += NTHREADS) scl[t] = 1.0f;
    }
    if (tid < COBT) {
        int co = g * COBT + tid;
        if (BN_RELU) {
            gl[tid] = gamma[co] * BN_INV_F;
            bl[tid] = beta[co];
        } else {
            gl[tid] = (kk == 0) ? gamma[co] : 0.0f;
        }
    }
    __syncthreads();

    stage(0, 0);
    stage(1, 1);

    float acc0[WCO], acc1[WCO];
#pragma unroll
    for (int co = 0; co < WCO; ++co) { acc0[co] = 0.0f; acc1[co] = 0.0f; }

    for (int c = 0; c < NCHUNK; ++c) {
        if (interior) {
            if (c + 1 < NCHUNK)
                asm volatile("s_waitcnt vmcnt(%0)" :: "i"(NPW) : "memory");
            else
                asm volatile("s_waitcnt vmcnt(0)" ::: "memory");
        } else {
            asm volatile("s_waitcnt vmcnt(0) lgkmcnt(0)" ::: "memory");
        }
        __builtin_amdgcn_s_barrier();
        __builtin_amdgcn_sched_barrier(0);
        if (c + 2 < NCHUNK) stage(c + 2, (c + 2) % 3);

        const float* bb = &in_t[c % 3][0];
#pragma unroll
        for (int ci = 0; ci < CB; ++ci) {
            const int cw = cin0 + c * CB + ci;
            const float sc = scl[cw];
            const float* wtap = wt + (size_t)cw * 9 * COUT + g * COBT + wvu * WCO;
            const float* bb_ci = bb + ci * IH_T * WIN;
#pragma unroll
            for (int kh = 0; kh < 3; ++kh) {
                const float* row = bb_ci + (rl * STRIDE + kh) * WIN;
                // 3 LDS instrs: E pair (b64), O pair (b64), O[-1] (b32)
                float2 E2 = *(const float2*)(row + 2 * wo2);
                float2 O2 = *(const float2*)(row + HALF + 2 * wo2);
                float om = row[HALF + ((wo2 == 0) ? 0 : (2 * wo2 - 1))];
                if (wo2 == 0) om = 0.0f;
                const float vm0 = om   * sc;   // c0 kw0
                const float ve0 = E2.x * sc;   // c0 kw1
                const float vp0 = O2.x * sc;   // c0 kw2 == c1 kw0
                const float ve1 = E2.y * sc;   // c1 kw1
                const float vp1 = O2.y * sc;   // c1 kw2
                const float* w0 = wtap + (kh * 3 + 0) * COUT;  // uniform -> SGPR
                const float* w1 = wtap + (kh * 3 + 1) * COUT;
                const float* w2 = wtap + (kh * 3 + 2) * COUT;
#pragma unroll
                for (int co = 0; co < WCO; ++co) {
                    acc0[co] = fmaf(w0[co], vm0, acc0[co]);
                    acc0[co] = fmaf(w1[co], ve0, acc0[co]);
                    acc0[co] = fmaf(w2[co], vp0, acc0[co]);
                    acc1[co] = fmaf(w0[co], vp0, acc1[co]);
                    acc1[co] = fmaf(w1[co], ve1, acc1[co]);
                    acc1[co] = fmaf(w2[co], vp1, acc1[co]);
                }
            }
        }
    }

    float tsum[WCO];
#pragma unroll
    for (int co = 0; co < WCO; ++co) tsum[co] = 0.0f;
    const int ho = ty * TH + rl;
    float* ob = out + ((size_t)b * COUT + (size_t)g * COBT + (size_t)wvu * WCO) * HOUT * WOUT;
#pragma unroll
    for (int co = 0; co < WCO; ++co) {
        float v0, v1;
        const float gg = gl[wvu * WCO + co];
        if (BN_RELU) {
            const float bb2 = bl[wvu * WCO + co];
            v0 = fmaxf(fmaf(acc0[co], gg, bb2), 0.0f);
            v1 = fmaxf(fmaf(acc1[co], gg, bb2), 0.0f);
        } else {
            v0 = acc0[co] + gg;
            v1 = acc1[co] + gg;
        }
        float2 vv; vv.x = v0; vv.y = v1;
        *(float2*)(ob + (size_t)co * HOUT * WOUT + (size_t)ho * WOUT + 2 * wo2) = vv;
        tsum[co] += v0 + v1;
    }

    if (SE_SUM) {
#pragma unroll
        for (int co = 0; co < WCO; ++co) {
            float v = tsum[co];
            for (int off = 32; off; off >>= 1) v += __shfl_down(v, off, 64);
            if (lane == 0) red[wvu][co] = v;
        }
        __syncthreads();
        if (lane < WCO)
            atomicAdd(&se_sum[b * COUT + g * COBT + wvu * WCO + lane], red[wvu][lane]);
    }
}

#define CONV_ARGS \
    const float* __restrict__ in, const float* __restrict__ wt, \
    const float* __restrict__ gamma, const float* __restrict__ beta, \
    float* __restrict__ out, size_t pstride, float* __restrict__ se_sum, \
    const float* __restrict__ se_sums_in, \
    const float* __restrict__ se_w1, const float* __restrict__ se_b1, \
    const float* __restrict__ se_w2, const float* __restrict__ se_b2, \
    float inv_spatial
#define CONV_PASS in, wt, gamma, beta, out, pstride, se_sum, se_sums_in, \
    se_w1, se_b1, se_w2, se_b2, inv_spatial
#define CONV_PASS2 in, wt, gamma, beta, out, se_sum, se_sums_in, \
    se_w1, se_b1, se_w2, se_b2, inv_spatial

__global__ __launch_bounds__(256) void conv1_k(CONV_ARGS) {
    conv_body<1, 1, 16, 16, 128, 128, 1, 128, 2, 2, 1, 256, true, true, 0, 1>(CONV_PASS);
}
// conv2: 4 waves x 8 couts, 2-col threads (32 pairs x 2 rows), CB=4. 2048 blocks.
__global__ __launch_bounds__(256) void conv2_k(CONV_ARGS) {
    conv_ws2_body<16, 16, 32, 8, 128, 64, 64, 4, 256, true, true, 1>(CONV_PASS2);
}
// conv3: 4 waves x 8 couts (NG=2), 2-col threads (16 pairs x 4 rows), CB=4. 1024 blocks.
__global__ __launch_bounds__(256) void conv3_k(CONV_ARGS) {
    conv_ws2_body<32, 32, 64, 8, 64, 32, 32, 4, 256, true, true, 2>(CONV_PASS2);
}
__global__ __launch_bounds__(256) void pc_k(CONV_ARGS) {
    conv_body<64, 16, 64, 16, 32, 16, 2, 16, 16, 1, 4, 256, false, false, 4, 4>(CONV_PASS);
}

// ---------------------------------------------------------------------------
// Fused squash + u_hat. Block = 256 capsules.
// ---------------------------------------------------------------------------
__global__ __launch_bounds__(256) void squash_uhat_k(
    const float* __restrict__ up, size_t pstride,
    const float* __restrict__ W, float* __restrict__ u_hat)
{
    const int base = blockIdx.x * 256;
    const int tid = threadIdx.x;
    __shared__ float ush[256][8];

    {
        const int cap = base + tid;
        const int b = cap >> 11, i = cap & 2047;
        const int chi = i >> 8, spx = i & 255;
        const size_t off = ((size_t)(b * 64 + chi * 8)) * 256 + spx;
        float s[8];
        float n2 = 0.0f;
#pragma unroll
        for (int j = 0; j < 8; j++) {
            const size_t o = off + (size_t)j * 256;
            s[j] = (up[o] + up[o + pstride]) + (up[o + 2 * pstride] + up[o + 3 * pstride]);
            n2 = fmaf(s[j], s[j], n2);
        }
        const float n = sqrtf(n2);
        const float f = (n2 / (1.0f + n2)) / (n + 1e-8f);
#pragma unroll
        for (int j = 0; j < 8; j++) ush[tid][j] = s[j] * f;
    }
    __syncthreads();

    float* ob = u_hat + (size_t)base * 48;
#pragma unroll 4
    for (int k = 0; k < 48; ++k) {
        int o = tid + k * 256;
        int c = o / 48, cd = o % 48;
        int gi = (base + c) & 2047;
        const float* wp = W + (size_t)gi * 384 + cd * 8;
        float a = 0.0f;
#pragma unroll
        for (int e = 0; e < 8; e++) a = fmaf(wp[e], ush[c][e], a);
        ob[o] = a;
    }
}

// ---------------------------------------------------------------------------
template <int IT>
__global__ __launch_bounds__(256) void sweep_k(const float* __restrict__ u_hat,
                                               const float* __restrict__ s_hist,
                                               float* __restrict__ s_out)
{
    const int b = blockIdx.y;
    const int i = blockIdx.x * 256 + threadIdx.x;
    const int tid = threadIdx.x;
    __shared__ float vsh[IT > 0 ? IT : 1][48];
    __shared__ float fac[IT > 0 ? IT : 1][3];
    __shared__ float red[4][48];

    const float4* qp = (const float4*)(u_hat + ((size_t)b * 2048 + i) * 48);
    float uhv[48];
#pragma unroll
    for (int q = 0; q < 12; ++q) {
        float4 t = qp[q];
        uhv[q * 4 + 0] = t.x; uhv[q * 4 + 1] = t.y;
        uhv[q * 4 + 2] = t.z; uhv[q * 4 + 3] = t.w;
    }

    if (IT > 0) {
        if (tid < IT * 48) {
            int t = tid / 48, c = tid % 48;
            vsh[t][c] = s_hist[((size_t)t * 64 + b) * 48 + c];
        }
        __syncthreads();
        if (tid < IT * 3) {
            int t = tid / 3, j = tid % 3;
            float n2 = 0.0f;
            for (int d = 0; d < 16; ++d) { float s = vsh[t][j * 16 + d]; n2 = fmaf(s, s, n2); }
            float n = sqrtf(n2);
            fac[t][j] = (n2 / (1.0f + n2)) / (n + 1e-8f);
        }
        __syncthreads();
        if (tid < IT * 48) {
            int t = tid / 48, c = tid % 48;
            vsh[t][c] *= fac[t][c / 16];
        }
        __syncthreads();
    }

    float c0, c1, c2;
    if (IT == 0) {
        c0 = c1 = c2 = (1.0f / 3.0f);
    } else {
        float b0 = 0.0f, b1 = 0.0f, b2 = 0.0f;
#pragma unroll
        for (int t = 0; t < IT; ++t)
#pragma unroll
            for (int d = 0; d < 16; ++d) {
                b0 = fmaf(uhv[d],      vsh[t][d],      b0);
                b1 = fmaf(uhv[16 + d], vsh[t][16 + d], b1);
                b2 = fmaf(uhv[32 + d], vsh[t][32 + d], b2);
            }
        float m = fmaxf(b0, fmaxf(b1, b2));
        float e0 = expf(b0 - m), e1 = expf(b1 - m), e2 = expf(b2 - m);
        float inv = 1.0f / (e0 + e1 + e2);
        c0 = e0 * inv; c1 = e1 * inv; c2 = e2 * inv;
    }

    float sp[48];
#pragma unroll
    for (int d = 0; d < 16; ++d) {
        sp[d]      = c0 * uhv[d];
        sp[16 + d] = c1 * uhv[16 + d];
        sp[32 + d] = c2 * uhv[32 + d];
    }
    const int lane = tid & 63, wv = tid >> 6;
#pragma unroll
    for (int j = 0; j < 48; ++j) {
        float x = sp[j];
        for (int off = 32; off; off >>= 1) x += __shfl_down(x, off, 64);
        if (lane == 0) red[wv][j] = x;
    }
    __syncthreads();
    if (tid < 48) {
        float x = red[0][tid] + red[1][tid] + red[2][tid] + red[3][tid];
        atomicAdd(&s_out[(size_t)b * 48 + tid], x);
    }
}

// ---------------------------------------------------------------------------
__global__ __launch_bounds__(64) void route_out_k(const float* __restrict__ s2,
                                                  float* __restrict__ out)
{
    const int b = blockIdx.x;
    __shared__ float s[48];
    if (threadIdx.x < 48) s[threadIdx.x] = s2[(size_t)b * 48 + threadIdx.x];
    __syncthreads();
    if (threadIdx.x < 3) {
        int j = threadIdx.x;
        float n2 = 0.0f;
        for (int d = 0; d < 16; ++d) { float v = s[j * 16 + d]; n2 = fmaf(v, v, n2); }
        float n = sqrtf(n2);
        float fc = (n2 / (1.0f + n2)) / (n + 1e-8f);
        out[b * 3 + j] = fc * n;
    }
}

// ---------------------------------------------------------------------------
extern "C" void kernel_launch(void* const* d_in, const int* in_sizes, int n_in,
                              void* d_out, int out_size, void* d_ws, size_t ws_size,
                              hipStream_t stream)
{
    const float* x       = (const float*)d_in[0];
    const float* conv1_w = (const float*)d_in[1];
    const float* bn1_g   = (const float*)d_in[2];
    const float* bn1_b   = (const float*)d_in[3];
    const float* se1_w1  = (const float*)d_in[4];
    const float* se1_b1  = (const float*)d_in[5];
    const float* se1_w2  = (const float*)d_in[6];
    const float* se1_b2  = (const float*)d_in[7];
    const float* conv2_w = (const float*)d_in[8];
    const float* bn2_g   = (const float*)d_in[9];
    const float* bn2_b   = (const float*)d_in[10];
    const float* se2_w1  = (const float*)d_in[11];
    const float* se2_b1  = (const float*)d_in[12];
    const float* se2_w2  = (const float*)d_in[13];
    const float* se2_b2  = (const float*)d_in[14];
    const float* conv3_w = (const float*)d_in[15];
    const float* bn3_g   = (const float*)d_in[16];
    const float* bn3_b   = (const float*)d_in[17];
    const float* se3_w1  = (const float*)d_in[18];
    const float* se3_b1  = (const float*)d_in[19];
    const float* se3_w2  = (const float*)d_in[20];
    const float* se3_b2  = (const float*)d_in[21];
    const float* pc_w    = (const float*)d_in[22];
    const float* pc_b    = (const float*)d_in[23];
    const float* W_digit = (const float*)d_in[24];  // (1,2048,3,16,8)

    float* ws = (float*)d_ws;
    float* h1     = ws;
    float* h2     = ws + 16777216;
    float* h3     = ws;                  // overlays dead h1 (conv3 writes here)
    float* uparts = ws + 4194304;
    float* u_hat  = ws + 9437184;
    float* sums   = ws + 25165824;
    float* s1 = sums, *s2 = sums + 1024, *s3 = sums + 3072;
    float* s_buf  = sums + 7168;
    float* w1t    = ws + 25182272;
    float* w2t    = w1t + 144;
    float* w3t    = w2t + 4608;
    float* wpt    = w3t + 18432;

    hipMemsetAsync(sums, 0, 16448 * sizeof(float), stream);
    wtrans_all_k<<<235, 256, 0, stream>>>(conv1_w, conv2_w, conv3_w, pc_w,
                                          w1t, w2t, w3t, wpt);

    // conv1: 1->16, 128x128, s1. 2048 blocks.
    conv1_k<<<dim3(32, 1, 64), 256, 0, stream>>>(
        x, w1t, bn1_g, bn1_b, h1, 0, s1,
        nullptr, nullptr, nullptr, nullptr, nullptr, 0.0f);

    // conv2: 16->32, ->64x64, s2. 2-col wave-split, TH=2, CB=4. 2048 blocks.
    conv2_k<<<dim3(32, 1, 64), 256, 0, stream>>>(
        h1, w2t, bn2_g, bn2_b, h2, 0, s2,
        s1, se1_w1, se1_b1, se1_w2, se1_b2, 1.0f / 16384.0f);

    // conv3: 32->64, ->32x32, s2. 2-col wave-split, TH=4, CB=4, NG=2. 1024 blocks.
    conv3_k<<<dim3(8, 2, 64), 256, 0, stream>>>(
        h2, w3t, bn3_g, bn3_b, h3, 0, s3,
        s2, se2_w1, se2_b1, se2_w2, se2_b2, 1.0f / 4096.0f);

    // primary caps: 64->64, ->16x16, s2, +bias. COB=16/NG=4, KSPLIT=4, CB=4.
    pc_k<<<dim3(1, 16, 64), 256, 0, stream>>>(
        h3, wpt, pc_b, nullptr, uparts, (size_t)1048576, nullptr,
        s3, se3_w1, se3_b1, se3_w2, se3_b2, 1.0f / 1024.0f);

    squash_uhat_k<<<512, 256, 0, stream>>>(uparts, (size_t)1048576, W_digit, u_hat);

    sweep_k<0><<<dim3(8, 64), 256, 0, stream>>>(u_hat, s_buf, s_buf + 0 * 64 * 48);
    sweep_k<1><<<dim3(8, 64), 256, 0, stream>>>(u_hat, s_buf, s_buf + 1 * 64 * 48);
    sweep_k<2><<<dim3(8, 64), 256, 0, stream>>>(u_hat, s_buf, s_buf + 2 * 64 * 48);
    route_out_k<<<64, 64, 0, stream>>>(s_buf + 2 * 64 * 48, (float*)d_out);
}

// Round 18
// 212.195 us; speedup vs baseline: 1.0734x; 1.0016x over previous
//
#include <hip/hip_runtime.h>
#include <math.h>

#define BN_INV_F 0.9999950000374997f

__device__ __forceinline__ void gload_lds4(const float* g, float* l) {
    __builtin_amdgcn_global_load_lds(
        (const __attribute__((address_space(1))) void*)g,
        (__attribute__((address_space(3))) void*)l, 4, 0, 0);
}
__device__ __forceinline__ void gload_lds16(const float* g, float* l) {
    __builtin_amdgcn_global_load_lds(
        (const __attribute__((address_space(1))) void*)g,
        (__attribute__((address_space(3))) void*)l, 16, 0, 0);
}

// ---------------------------------------------------------------------------
// Weight transpose (once): wt[(cin*9+k)*COUT + co] = w[co][cin][k]
// ---------------------------------------------------------------------------
__global__ __launch_bounds__(256) void wtrans_all_k(
    const float* __restrict__ w1, const float* __restrict__ w2,
    const float* __restrict__ w3, const float* __restrict__ wp,
    float* __restrict__ w1t, float* __restrict__ w2t,
    float* __restrict__ w3t, float* __restrict__ wpt)
{
    int i = blockIdx.x * 256 + threadIdx.x;
    if (i < 144) {
        int co = i % 16, k = i / 16;
        w1t[i] = w1[co * 9 + k];
    } else if (i < 4752) {
        int t = i - 144;
        int co = t % 32, rk = t / 32, cin = rk / 9, k = rk % 9;
        w2t[t] = w2[(co * 16 + cin) * 9 + k];
    } else if (i < 23184) {
        int t = i - 4752;
        int co = t % 64, rk = t / 64, cin = rk / 9, k = rk % 9;
        w3t[t] = w3[(co * 32 + cin) * 9 + k];
    } else if (i < 60048) {
        int t = i - 23184;
        int co = t % 64, rk = t / 64, cin = rk / 9, k = rk % 9;
        wpt[t] = wp[(co * 64 + cin) * 9 + k];
    }
}

// ---------------------------------------------------------------------------
// Original conv body (conv1 / pc): thread-split couts, 2-buffer drain scheme.
// ---------------------------------------------------------------------------
template <int CIN, int CINB, int COUT, int COB, int HIN, int HOUT, int STRIDE,
          int TW, int ROWS_T, int PPT, int CB, int NTHREADS,
          bool BN_RELU, bool SE_SUM, int HSE_IN, int KSPLIT>
__device__ __forceinline__ void conv_body(
    const float* __restrict__ in, const float* __restrict__ wt,
    const float* __restrict__ gamma, const float* __restrict__ beta,
    float* __restrict__ out, size_t pstride,
    float* __restrict__ se_sum, const float* __restrict__ se_sums_in,
    const float* __restrict__ se_w1, const float* __restrict__ se_b1,
    const float* __restrict__ se_w2, const float* __restrict__ se_b2,
    float inv_spatial)
{
    constexpr int WIN = HIN, WOUT = HOUT;
    constexpr int TH = ROWS_T * PPT;
    constexpr int IH_T = (TH - 1) * STRIDE + 3;
    constexpr int NW = NTHREADS / 64;
    constexpr int NCHUNK = CINB / CB;
    constexpr int SEGS = (WIN >= 64) ? (WIN / 64) : 1;
    constexpr int PAIRS = (IH_T + 1) / 2;
    constexpr int NG = COUT / COB;
    constexpr int IHW = IH_T * WIN;
    constexpr int CHUNK_BYTES = CB * IHW * 4;
    constexpr bool FAST16 = (CHUNK_BYTES % 1024) == 0;
    constexpr int NISS = CHUNK_BYTES / 1024;
    static_assert(NTHREADS == TW * ROWS_T, "geometry");
    static_assert(TW == WOUT, "tile must span full output width");
    static_assert(CINB % CB == 0, "chunking");
    static_assert(WIN % 64 == 0 || WIN == 32, "stage width");

    const int b = blockIdx.z;
    const int gy = blockIdx.y;
    const int ty = blockIdx.x;
    const int tid = threadIdx.x;
    const int wo = tid % TW;
    const int rg = tid / TW;
    const int g = gy % NG;
    const int kk = gy / NG;
    const int cin0 = kk * CINB;

    __shared__ float in_t[2][CB * IH_T * WIN];
    __shared__ float scl[CIN];
    __shared__ float gl[COB], bl[COB];
    __shared__ float red[NW][COB];
    __shared__ float hid[HSE_IN > 0 ? HSE_IN : 1];

    const float* inb = in + (size_t)b * CIN * HIN * WIN;
    const int gr0 = ty * TH * STRIDE - 1;
    const int wos = wo * STRIDE;
    const int wvid = tid >> 6, lane = tid & 63;
    const bool interior = (gr0 >= 0) && (gr0 + IH_T <= HIN);

    auto stage = [&](int c, int buf) {
        const int cb0 = cin0 + c * CB;
        float* bb = &in_t[buf][0];
        if (FAST16 && interior) {
            for (int i = wvid; i < NISS; i += NW) {
                int fe = i * 256 + lane * 4;
                int ci = fe / IHW;
                int rem = fe - ci * IHW;
                int lr = rem / WIN;
                int lc = rem - lr * WIN;
                const float* gsrc = inb + (size_t)(cb0 + ci) * (HIN * WIN)
                                  + (size_t)(gr0 + lr) * WIN + lc;
                gload_lds16(gsrc, bb + i * 256);
            }
        } else if (WIN >= 64) {
            for (int r = wvid; r < CB * IH_T; r += NW) {
                int ci = r / IH_T, lr = r - ci * IH_T;
                int gr = gr0 + lr;
                float* ldst = bb + (ci * IH_T + lr) * WIN;
                if (gr >= 0 && gr < HIN) {
                    const float* gsrc = inb + (size_t)(cb0 + ci) * HIN * WIN + (size_t)gr * WIN;
#pragma unroll
                    for (int s = 0; s < SEGS; ++s)
                        gload_lds4(gsrc + s * 64 + lane, ldst + s * 64);
                } else {
#pragma unroll
                    for (int s = 0; s < SEGS; ++s) ldst[s * 64 + lane] = 0.0f;
                }
            }
        } else {
            for (int pz = wvid; pz < CB * PAIRS; pz += NW) {
                int ci = pz / PAIRS, q = pz - ci * PAIRS;
                int lr0 = q * 2;
                int nr = (lr0 + 1 < IH_T) ? 2 : 1;
                int grr = gr0 + lr0;
                float* ldst = bb + (ci * IH_T + lr0) * WIN;
                if (nr == 2 && grr >= 0 && grr + 1 < HIN) {
                    const float* gsrc = inb + (size_t)(cb0 + ci) * HIN * WIN + (size_t)grr * WIN + lane;
                    gload_lds4(gsrc, ldst);
                } else {
                    for (int e = lane; e < nr * WIN; e += 64) {
                        int rr = e / WIN, cc = e - rr * WIN;
                        int gr = grr + rr;
                        ldst[e] = (gr >= 0 && gr < HIN)
                            ? inb[(size_t)(cb0 + ci) * HIN * WIN + (size_t)gr * WIN + cc] : 0.0f;
                    }
                }
            }
        }
    };

    stage(0, 0);

    if (HSE_IN > 0) {
        if (tid < HSE_IN) {
            float a = se_b1[tid];
            for (int c = 0; c < CIN; ++c)
                a = fmaf(se_sums_in[b * CIN + c] * inv_spatial, se_w1[tid * CIN + c], a);
            hid[tid] = fmaxf(a, 0.0f);
        }
        __syncthreads();
        if (tid < CIN) {
            float a = se_b2[tid];
            for (int h = 0; h < HSE_IN; ++h)
                a = fmaf(hid[h], se_w2[tid * HSE_IN + h], a);
            scl[tid] = 1.0f / (1.0f + expf(-a));
        }
    } else {
        for (int t = tid; t < CIN; t += NTHREADS) scl[t] = 1.0f;
    }
    if (tid < COB) {
        int co = g * COB + tid;
        if (BN_RELU) {
            gl[tid] = gamma[co] * BN_INV_F;
            bl[tid] = beta[co];
        } else {
            gl[tid] = (kk == 0) ? gamma[co] : 0.0f;
        }
    }

    float acc[PPT][COB];
#pragma unroll
    for (int p = 0; p < PPT; ++p)
#pragma unroll
        for (int co = 0; co < COB; ++co) acc[p][co] = 0.0f;

    int cur = 0;
    for (int c = 0; c < NCHUNK; ++c) {
        asm volatile("s_waitcnt vmcnt(0)" ::: "memory");
        __syncthreads();
        if (c + 1 < NCHUNK) stage(c + 1, cur ^ 1);

        const float* bb = &in_t[cur][0];
#pragma unroll
        for (int ci = 0; ci < CB; ++ci) {
            const int cw = cin0 + c * CB + ci;
            const float sc = scl[cw];
            const float* wtap = wt + (size_t)cw * 9 * COUT + g * COB;
            const float* bb_ci = bb + ci * IH_T * WIN;
#pragma unroll
            for (int kh = 0; kh < 3; ++kh) {
#pragma unroll
                for (int kw = 0; kw < 3; ++kw) {
                    const float* wrow = wtap + (kh * 3 + kw) * COUT;
#pragma unroll
                    for (int p = 0; p < PPT; ++p) {
                        const float* row = bb_ci + ((rg + p * ROWS_T) * STRIDE + kh) * WIN;
                        int wi = wos + kw - 1;
                        float v;
                        if (kw == 0) {
                            v = row[wi < 0 ? 0 : wi];
                            if (wi < 0) v = 0.0f;
                        } else if (STRIDE == 1 && kw == 2) {
                            v = row[wi >= WIN ? WIN - 1 : wi];
                            if (wi >= WIN) v = 0.0f;
                        } else {
                            v = row[wi];
                        }
                        v *= sc;
#pragma unroll
                        for (int co = 0; co < COB; ++co)
                            acc[p][co] = fmaf(wrow[co], v, acc[p][co]);
                    }
                }
            }
        }
        cur ^= 1;
    }

    float tsum[COB];
#pragma unroll
    for (int co = 0; co < COB; ++co) tsum[co] = 0.0f;
    float* ob = out + (size_t)kk * pstride
              + ((size_t)b * COUT + (size_t)g * COB) * HOUT * WOUT;
#pragma unroll
    for (int p = 0; p < PPT; ++p) {
        const int ho = ty * TH + rg + p * ROWS_T;
#pragma unroll
        for (int co = 0; co < COB; ++co) {
            float v;
            if (BN_RELU)
                v = fmaxf(fmaf(acc[p][co], gl[co], bl[co]), 0.0f);
            else
                v = acc[p][co] + gl[co];
            ob[(size_t)co * HOUT * WOUT + ho * WOUT + wo] = v;
            tsum[co] += v;
        }
    }

    if (SE_SUM) {
#pragma unroll
        for (int co = 0; co < COB; ++co) {
            float v = tsum[co];
            for (int off = 32; off; off >>= 1) v += __shfl_down(v, off, 64);
            if (lane == 0) red[wvid][co] = v;
        }
        __syncthreads();
        if (tid < COB) {
            float v = 0.0f;
#pragma unroll
            for (int k = 0; k < NW; ++k) v += red[k][tid];
            atomicAdd(&se_sum[b * COUT + g * COB + tid], v);
        }
    }
}

// ---------------------------------------------------------------------------
// Wave-split 2-col conv body (conv2 / conv3), STRIDE==2, de-interleaved LDS
// rows [E|O]. Thread owns a COLUMN PAIR: per (cin,kh) it reads E pair (b64)
// + O pair (b64) = 2 LDS instrs; O[2w-1] comes from the PREVIOUS LANE's O2.y
// via __shfl_up (VALU, no LDS). float2 output stores.
// Two-deep counted-vmcnt pipeline (3 buffers).
// ---------------------------------------------------------------------------
template <int CIN, int CINB, int COUT, int WCO, int HIN, int HOUT,
          int TW, int CB, int NTHREADS,
          bool BN_RELU, bool SE_SUM, int HSE_IN>
__device__ __forceinline__ void conv_ws2_body(
    const float* __restrict__ in, const float* __restrict__ wt,
    const float* __restrict__ gamma, const float* __restrict__ beta,
    float* __restrict__ out,
    float* __restrict__ se_sum, const float* __restrict__ se_sums_in,
    const float* __restrict__ se_w1, const float* __restrict__ se_b1,
    const float* __restrict__ se_w2, const float* __restrict__ se_b2,
    float inv_spatial)
{
    constexpr int WIN = HIN, WOUT = HOUT;
    constexpr int STRIDE = 2;
    constexpr int NW = NTHREADS / 64;
    constexpr int NP = TW / 2;                // col-pairs per row
    constexpr int TH = 64 / NP;               // rows per wave
    constexpr int IH_T = (TH - 1) * STRIDE + 3;
    constexpr int COBT = NW * WCO;
    constexpr int NG = COUT / COBT;
    constexpr int NCHUNK = CINB / CB;
    constexpr int SEGS = WIN / 64;
    constexpr int HALF = WIN / 2;
    constexpr int ROWS = CB * IH_T;
    constexpr int NPW = (ROWS / NW) * SEGS;   // DMAs per wave per stage (interior)
    static_assert(TW == WOUT, "tile spans full width");
    static_assert(CINB % CB == 0, "chunking");
    static_assert(WIN % 64 == 0, "stage width");
    static_assert(COUT % COBT == 0, "cout split");
    static_assert(ROWS % NW == 0, "uniform DMA count per wave");
    static_assert(NCHUNK >= 2, "pipeline depth");

    const int b = blockIdx.z;
    const int gy = blockIdx.y;
    const int ty = blockIdx.x;
    const int tid = threadIdx.x;
    const int lane = tid & 63;
    const int wvu = __builtin_amdgcn_readfirstlane(tid >> 6);
    const int wo2 = lane % NP;                // col pair index
    const int rl = lane / NP;                 // row within tile
    const int g = gy % NG;
    const int kk = gy / NG;
    const int cin0 = kk * CINB;

    __shared__ float in_t[3][CB * IH_T * WIN];
    __shared__ float scl[CIN];
    __shared__ float gl[COBT], bl[COBT];
    __shared__ float red[NW][WCO];
    __shared__ float hid[HSE_IN > 0 ? HSE_IN : 1];

    const float* inb = in + (size_t)b * CIN * HIN * WIN;
    const int gr0 = ty * TH * STRIDE - 1;
    const bool interior = (gr0 >= 0) && (gr0 + IH_T <= HIN);

    // de-interleaved staging: LDS row = [E(HALF) | O(HALF)]; 4B DMA, per-lane src
    auto stage = [&](int c, int buf) {
        const int cb0 = cin0 + c * CB;
        float* bb = &in_t[buf][0];
        if (interior) {
            for (int r = wvu; r < ROWS; r += NW) {
                int ci = r / IH_T, lr = r - ci * IH_T;
                const float* gsrc = inb + (size_t)(cb0 + ci) * HIN * WIN + (size_t)(gr0 + lr) * WIN;
                float* ldst = bb + r * WIN;
#pragma unroll
                for (int s = 0; s < SEGS; ++s) {
                    int p = s * 64 + lane;
                    int half = p / HALF;
                    int idx = p - half * HALF;
                    gload_lds4(gsrc + 2 * idx + half, ldst + s * 64);
                }
            }
        } else {
            for (int r = wvu; r < ROWS; r += NW) {
                int ci = r / IH_T, lr = r - ci * IH_T;
                int gr = gr0 + lr;
                float* ldst = bb + r * WIN;
                if (gr >= 0 && gr < HIN) {
                    const float* gsrc = inb + (size_t)(cb0 + ci) * HIN * WIN + (size_t)gr * WIN;
#pragma unroll
                    for (int s = 0; s < SEGS; ++s) {
                        int p = s * 64 + lane;
                        int half = p / HALF;
                        int idx = p - half * HALF;
                        gload_lds4(gsrc + 2 * idx + half, ldst + s * 64);
                    }
                } else {
#pragma unroll
                    for (int s = 0; s < SEGS; ++s) ldst[s * 64 + lane] = 0.0f;
                }
            }
        }
    };

    // ---- SE scale / BN params (before any DMA) ----
    if (HSE_IN > 0) {
        if (tid < HSE_IN) {
            float a = se_b1[tid];
            for (int c = 0; c < CIN; ++c)
                a = fmaf(se_sums_in[b * CIN + c] * inv_spatial, se_w1[tid * CIN + c], a);
            hid[tid] = fmaxf(a, 0.0f);
        }
        __syncthreads();
        if (tid < CIN) {
            float a = se_b2[tid];
            for (int h = 0; h < HSE_IN; ++h)
                a = fmaf(hid[h], se_w2[tid * HSE_IN + h], a);
            scl[tid] = 1.0f / (1.0f + expf(-a));
        }
    } else {
        for (int t = tid; t < CIN; t += NTHREADS) scl[t] = 1.0f;
    }
    if (tid < COBT) {
        int co = g * COBT + tid;
        if (BN_RELU) {
            gl[tid] = gamma[co] * BN_INV_F;
            bl[tid] = beta[co];
        } else {
            gl[tid] = (kk == 0) ? gamma[co] : 0.0f;
        }
    }
    __syncthreads();

    stage(0, 0);
    stage(1, 1);

    float acc0[WCO], acc1[WCO];
#pragma unroll
    for (int co = 0; co < WCO; ++co) { acc0[co] = 0.0f; acc1[co] = 0.0f; }

    for (int c = 0; c < NCHUNK; ++c) {
        if (interior) {
            if (c + 1 < NCHUNK)
                asm volatile("s_waitcnt vmcnt(%0)" :: "i"(NPW) : "memory");
            else
                asm volatile("s_waitcnt vmcnt(0)" ::: "memory");
        } else {
            asm volatile("s_waitcnt vmcnt(0) lgkmcnt(0)" ::: "memory");
        }
        __builtin_amdgcn_s_barrier();
        __builtin_amdgcn_sched_barrier(0);
        if (c + 2 < NCHUNK) stage(c + 2, (c + 2) % 3);

        const float* bb = &in_t[c % 3][0];
#pragma unroll
        for (int ci = 0; ci < CB; ++ci) {
            const int cw = cin0 + c * CB + ci;
            const float sc = scl[cw];
            const float* wtap = wt + (size_t)cw * 9 * COUT + g * COBT + wvu * WCO;
            const float* bb_ci = bb + ci * IH_T * WIN;
#pragma unroll
            for (int kh = 0; kh < 3; ++kh) {
                const float* row = bb_ci + (rl * STRIDE + kh) * WIN;
                // 2 LDS instrs: E pair (b64), O pair (b64); O[2w-1] via shuffle
                float2 E2 = *(const float2*)(row + 2 * wo2);
                float2 O2 = *(const float2*)(row + HALF + 2 * wo2);
                float om = __shfl_up(O2.y, 1, 64);   // prev lane's O[2w+1] = O[2w-1]
                if (wo2 == 0) om = 0.0f;             // tile-left boundary (and row seams)
                const float vm0 = om   * sc;   // c0 kw0
                const float ve0 = E2.x * sc;   // c0 kw1
                const float vp0 = O2.x * sc;   // c0 kw2 == c1 kw0
                const float ve1 = E2.y * sc;   // c1 kw1
                const float vp1 = O2.y * sc;   // c1 kw2
                const float* w0 = wtap + (kh * 3 + 0) * COUT;  // uniform -> SGPR
                const float* w1 = wtap + (kh * 3 + 1) * COUT;
                const float* w2 = wtap + (kh * 3 + 2) * COUT;
#pragma unroll
                for (int co = 0; co < WCO; ++co) {
                    acc0[co] = fmaf(w0[co], vm0, acc0[co]);
                    acc0[co] = fmaf(w1[co], ve0, acc0[co]);
                    acc0[co] = fmaf(w2[co], vp0, acc0[co]);
                    acc1[co] = fmaf(w0[co], vp0, acc1[co]);
                    acc1[co] = fmaf(w1[co], ve1, acc1[co]);
                    acc1[co] = fmaf(w2[co], vp1, acc1[co]);
                }
            }
        }
    }

    float tsum[WCO];
#pragma unroll
    for (int co = 0; co < WCO; ++co) tsum[co] = 0.0f;
    const int ho = ty * TH + rl;
    float* ob = out + ((size_t)b * COUT + (size_t)g * COBT + (size_t)wvu * WCO) * HOUT * WOUT;
#pragma unroll
    for (int co = 0; co < WCO; ++co) {
        float v0, v1;
        const float gg = gl[wvu * WCO + co];
        if (BN_RELU) {
            const float bb2 = bl[wvu * WCO + co];
            v0 = fmaxf(fmaf(acc0[co], gg, bb2), 0.0f);
            v1 = fmaxf(fmaf(acc1[co], gg, bb2), 0.0f);
        } else {
            v0 = acc0[co] + gg;
            v1 = acc1[co] + gg;
        }
        float2 vv; vv.x = v0; vv.y = v1;
        *(float2*)(ob + (size_t)co * HOUT * WOUT + (size_t)ho * WOUT + 2 * wo2) = vv;
        tsum[co] += v0 + v1;
    }

    if (SE_SUM) {
#pragma unroll
        for (int co = 0; co < WCO; ++co) {
            float v = tsum[co];
            for (int off = 32; off; off >>= 1) v += __shfl_down(v, off, 64);
            if (lane == 0) red[wvu][co] = v;
        }
        __syncthreads();
        if (lane < WCO)
            atomicAdd(&se_sum[b * COUT + g * COBT + wvu * WCO + lane], red[wvu][lane]);
    }
}

#define CONV_ARGS \
    const float* __restrict__ in, const float* __restrict__ wt, \
    const float* __restrict__ gamma, const float* __restrict__ beta, \
    float* __restrict__ out, size_t pstride, float* __restrict__ se_sum, \
    const float* __restrict__ se_sums_in, \
    const float* __restrict__ se_w1, const float* __restrict__ se_b1, \
    const float* __restrict__ se_w2, const float* __restrict__ se_b2, \
    float inv_spatial
#define CONV_PASS in, wt, gamma, beta, out, pstride, se_sum, se_sums_in, \
    se_w1, se_b1, se_w2, se_b2, inv_spatial
#define CONV_PASS2 in, wt, gamma, beta, out, se_sum, se_sums_in, \
    se_w1, se_b1, se_w2, se_b2, inv_spatial

__global__ __launch_bounds__(256) void conv1_k(CONV_ARGS) {
    conv_body<1, 1, 16, 16, 128, 128, 1, 128, 2, 2, 1, 256, true, true, 0, 1>(CONV_PASS);
}
// conv2: 4 waves x 8 couts, 2-col threads (32 pairs x 2 rows), CB=4. 2048 blocks.
__global__ __launch_bounds__(256) void conv2_k(CONV_ARGS) {
    conv_ws2_body<16, 16, 32, 8, 128, 64, 64, 4, 256, true, true, 1>(CONV_PASS2);
}
// conv3: 4 waves x 8 couts (NG=2), 2-col threads (16 pairs x 4 rows), CB=4. 1024 blocks.
__global__ __launch_bounds__(256) void conv3_k(CONV_ARGS) {
    conv_ws2_body<32, 32, 64, 8, 64, 32, 32, 4, 256, true, true, 2>(CONV_PASS2);
}
__global__ __launch_bounds__(256) void pc_k(CONV_ARGS) {
    conv_body<64, 16, 64, 16, 32, 16, 2, 16, 16, 1, 4, 256, false, false, 4, 4>(CONV_PASS);
}

// ---------------------------------------------------------------------------
// Fused squash + u_hat. Block = 256 capsules.
// ---------------------------------------------------------------------------
__global__ __launch_bounds__(256) void squash_uhat_k(
    const float* __restrict__ up, size_t pstride,
    const float* __restrict__ W, float* __restrict__ u_hat)
{
    const int base = blockIdx.x * 256;
    const int tid = threadIdx.x;
    __shared__ float ush[256][8];

    {
        const int cap = base + tid;
        const int b = cap >> 11, i = cap & 2047;
        const int chi = i >> 8, spx = i & 255;
        const size_t off = ((size_t)(b * 64 + chi * 8)) * 256 + spx;
        float s[8];
        float n2 = 0.0f;
#pragma unroll
        for (int j = 0; j < 8; j++) {
            const size_t o = off + (size_t)j * 256;
            s[j] = (up[o] + up[o + pstride]) + (up[o + 2 * pstride] + up[o + 3 * pstride]);
            n2 = fmaf(s[j], s[j], n2);
        }
        const float n = sqrtf(n2);
        const float f = (n2 / (1.0f + n2)) / (n + 1e-8f);
#pragma unroll
        for (int j = 0; j < 8; j++) ush[tid][j] = s[j] * f;
    }
    __syncthreads();

    float* ob = u_hat + (size_t)base * 48;
#pragma unroll 4
    for (int k = 0; k < 48; ++k) {
        int o = tid + k * 256;
        int c = o / 48, cd = o % 48;
        int gi = (base + c) & 2047;
        const float* wp = W + (size_t)gi * 384 + cd * 8;
        float a = 0.0f;
#pragma unroll
        for (int e = 0; e < 8; e++) a = fmaf(wp[e], ush[c][e], a);
        ob[o] = a;
    }
}

// ---------------------------------------------------------------------------
template <int IT>
__global__ __launch_bounds__(256) void sweep_k(const float* __restrict__ u_hat,
                                               const float* __restrict__ s_hist,
                                               float* __restrict__ s_out)
{
    const int b = blockIdx.y;
    const int i = blockIdx.x * 256 + threadIdx.x;
    const int tid = threadIdx.x;
    __shared__ float vsh[IT > 0 ? IT : 1][48];
    __shared__ float fac[IT > 0 ? IT : 1][3];
    __shared__ float red[4][48];

    const float4* qp = (const float4*)(u_hat + ((size_t)b * 2048 + i) * 48);
    float uhv[48];
#pragma unroll
    for (int q = 0; q < 12; ++q) {
        float4 t = qp[q];
        uhv[q * 4 + 0] = t.x; uhv[q * 4 + 1] = t.y;
        uhv[q * 4 + 2] = t.z; uhv[q * 4 + 3] = t.w;
    }

    if (IT > 0) {
        if (tid < IT * 48) {
            int t = tid / 48, c = tid % 48;
            vsh[t][c] = s_hist[((size_t)t * 64 + b) * 48 + c];
        }
        __syncthreads();
        if (tid < IT * 3) {
            int t = tid / 3, j = tid % 3;
            float n2 = 0.0f;
            for (int d = 0; d < 16; ++d) { float s = vsh[t][j * 16 + d]; n2 = fmaf(s, s, n2); }
            float n = sqrtf(n2);
            fac[t][j] = (n2 / (1.0f + n2)) / (n + 1e-8f);
        }
        __syncthreads();
        if (tid < IT * 48) {
            int t = tid / 48, c = tid % 48;
            vsh[t][c] *= fac[t][c / 16];
        }
        __syncthreads();
    }

    float c0, c1, c2;
    if (IT == 0) {
        c0 = c1 = c2 = (1.0f / 3.0f);
    } else {
        float b0 = 0.0f, b1 = 0.0f, b2 = 0.0f;
#pragma unroll
        for (int t = 0; t < IT; ++t)
#pragma unroll
            for (int d = 0; d < 16; ++d) {
                b0 = fmaf(uhv[d],      vsh[t][d],      b0);
                b1 = fmaf(uhv[16 + d], vsh[t][16 + d], b1);
                b2 = fmaf(uhv[32 + d], vsh[t][32 + d], b2);
            }
        float m = fmaxf(b0, fmaxf(b1, b2));
        float e0 = expf(b0 - m), e1 = expf(b1 - m), e2 = expf(b2 - m);
        float inv = 1.0f / (e0 + e1 + e2);
        c0 = e0 * inv; c1 = e1 * inv; c2 = e2 * inv;
    }

    float sp[48];
#pragma unroll
    for (int d = 0; d < 16; ++d) {
        sp[d]      = c0 * uhv[d];
        sp[16 + d] = c1 * uhv[16 + d];
        sp[32 + d] = c2 * uhv[32 + d];
    }
    const int lane = tid & 63, wv = tid >> 6;
#pragma unroll
    for (int j = 0; j < 48; ++j) {
        float x = sp[j];
        for (int off = 32; off; off >>= 1) x += __shfl_down(x, off, 64);
        if (lane == 0) red[wv][j] = x;
    }
    __syncthreads();
    if (tid < 48) {
        float x = red[0][tid] + red[1][tid] + red[2][tid] + red[3][tid];
        atomicAdd(&s_out[(size_t)b * 48 + tid], x);
    }
}

// ---------------------------------------------------------------------------
__global__ __launch_bounds__(64) void route_out_k(const float* __restrict__ s2,
                                                  float* __restrict__ out)
{
    const int b = blockIdx.x;
    __shared__ float s[48];
    if (threadIdx.x < 48) s[threadIdx.x] = s2[(size_t)b * 48 + threadIdx.x];
    __syncthreads();
    if (threadIdx.x < 3) {
        int j = threadIdx.x;
        float n2 = 0.0f;
        for (int d = 0; d < 16; ++d) { float v = s[j * 16 + d]; n2 = fmaf(v, v, n2); }
        float n = sqrtf(n2);
        float fc = (n2 / (1.0f + n2)) / (n + 1e-8f);
        out[b * 3 + j] = fc * n;
    }
}

// ---------------------------------------------------------------------------
extern "C" void kernel_launch(void* const* d_in, const int* in_sizes, int n_in,
                              void* d_out, int out_size, void* d_ws, size_t ws_size,
                              hipStream_t stream)
{
    const float* x       = (const float*)d_in[0];
    const float* conv1_w = (const float*)d_in[1];
    const float* bn1_g   = (const float*)d_in[2];
    const float* bn1_b   = (const float*)d_in[3];
    const float* se1_w1  = (const float*)d_in[4];
    const float* se1_b1  = (const float*)d_in[5];
    const float* se1_w2  = (const float*)d_in[6];
    const float* se1_b2  = (const float*)d_in[7];
    const float* conv2_w = (const float*)d_in[8];
    const float* bn2_g   = (const float*)d_in[9];
    const float* bn2_b   = (const float*)d_in[10];
    const float* se2_w1  = (const float*)d_in[11];
    const float* se2_b1  = (const float*)d_in[12];
    const float* se2_w2  = (const float*)d_in[13];
    const float* se2_b2  = (const float*)d_in[14];
    const float* conv3_w = (const float*)d_in[15];
    const float* bn3_g   = (const float*)d_in[16];
    const float* bn3_b   = (const float*)d_in[17];
    const float* se3_w1  = (const float*)d_in[18];
    const float* se3_b1  = (const float*)d_in[19];
    const float* se3_w2  = (const float*)d_in[20];
    const float* se3_b2  = (const float*)d_in[21];
    const float* pc_w    = (const float*)d_in[22];
    const float* pc_b    = (const float*)d_in[23];
    const float* W_digit = (const float*)d_in[24];  // (1,2048,3,16,8)

    float* ws = (float*)d_ws;
    float* h1     = ws;
    float* h2     = ws + 16777216;
    float* h3     = ws;                  // overlays dead h1 (conv3 writes here)
    float* uparts = ws + 4194304;
    float* u_hat  = ws + 9437184;
    float* sums   = ws + 25165824;
    float* s1 = sums, *s2 = sums + 1024, *s3 = sums + 3072;
    float* s_buf  = sums + 7168;
    float* w1t    = ws + 25182272;
    float* w2t    = w1t + 144;
    float* w3t    = w2t + 4608;
    float* wpt    = w3t + 18432;

    hipMemsetAsync(sums, 0, 16448 * sizeof(float), stream);
    wtrans_all_k<<<235, 256, 0, stream>>>(conv1_w, conv2_w, conv3_w, pc_w,
                                          w1t, w2t, w3t, wpt);

    // conv1: 1->16, 128x128, s1. 2048 blocks.
    conv1_k<<<dim3(32, 1, 64), 256, 0, stream>>>(
        x, w1t, bn1_g, bn1_b, h1, 0, s1,
        nullptr, nullptr, nullptr, nullptr, nullptr, 0.0f);

    // conv2: 16->32, ->64x64, s2. 2-col wave-split, TH=2, CB=4. 2048 blocks.
    conv2_k<<<dim3(32, 1, 64), 256, 0, stream>>>(
        h1, w2t, bn2_g, bn2_b, h2, 0, s2,
        s1, se1_w1, se1_b1, se1_w2, se1_b2, 1.0f / 16384.0f);

    // conv3: 32->64, ->32x32, s2. 2-col wave-split, TH=4, CB=4, NG=2. 1024 blocks.
    conv3_k<<<dim3(8, 2, 64), 256, 0, stream>>>(
        h2, w3t, bn3_g, bn3_b, h3, 0, s3,
        s2, se2_w1, se2_b1, se2_w2, se2_b2, 1.0f / 4096.0f);

    // primary caps: 64->64, ->16x16, s2, +bias. COB=16/NG=4, KSPLIT=4, CB=4.
    pc_k<<<dim3(1, 16, 64), 256, 0, stream>>>(
        h3, wpt, pc_b, nullptr, uparts, (size_t)1048576, nullptr,
        s3, se3_w1, se3_b1, se3_w2, se3_b2, 1.0f / 1024.0f);

    squash_uhat_k<<<512, 256, 0, stream>>>(uparts, (size_t)1048576, W_digit, u_hat);

    sweep_k<0><<<dim3(8, 64), 256, 0, stream>>>(u_hat, s_buf, s_buf + 0 * 64 * 48);
    sweep_k<1><<<dim3(8, 64), 256, 0, stream>>>(u_hat, s_buf, s_buf + 1 * 64 * 48);
    sweep_k<2><<<dim3(8, 64), 256, 0, stream>>>(u_hat, s_buf, s_buf + 2 * 64 * 48);
    route_out_k<<<64, 64, 0, stream>>>(s_buf + 2 * 64 * 48, (float*)d_out);
}